// Round 5
// baseline (7157.185 us; speedup 1.0000x reference)
//
#include <hip/hip_runtime.h>
#include <math.h>

// ---------------------------------------------------------------------------
// AlexCapsNet (FOOD101) forward. Round 5: batch-folded implicit-GEMM convs
// with 128x128 / 64x128 tiles (8x8 / 4x8 per thread) to cut LDS traffic per
// FLOP 2-4x. Routing (LDS-staged W) and FC/pool kernels from round 4.
// ---------------------------------------------------------------------------

#define BATCH 64
#define NJ 101
#define NI 1152
#define BJ (BATCH * NJ)          // 6464
#define IC 64                    // routing i-chunk per block
#define NIC (NI / IC)            // 18
#define LDW 132                  // routing LDS row stride (words)

static inline int ceil_div(int a, int b) { return (a + b - 1) / b; }

// ---------------------------------------------------------------------------
// Implicit-GEMM conv, batch folded into pixel dim.
// C[co, p] = W[co, cin*K*K] x im2col[cin*K*K, p],  p = (b, ho, wo)
// Tile TCO x TPX (TCO,TPX in {64,128}), 256 threads, thread = (TCO/16)x(TPX/16).
// ---------------------------------------------------------------------------
template<int K, int STRIDE, int PAD, int WOUT, bool RELU, int TCO, int TPX>
__global__ __launch_bounds__(256, 2) void conv_igemm2(
        const float* __restrict__ in, const float* __restrict__ wgt,
        const float* __restrict__ bias, float* __restrict__ out,
        int CIN, int COUT, int WIN) {
    constexpr int KC   = 32;
    constexpr int NSP  = WOUT * WOUT;          // spatial pixels per image
    constexpr int CO_T = TCO / 16;             // 4 or 8 couts per thread
    constexpr int PX_T = TPX / 16;             // 4 or 8 pixels per thread
    constexpr int LDA  = TCO + 4;
    constexpr int LDB  = TPX + 4;
    __shared__ float Ash[KC * LDA];            // [kk][co]
    __shared__ float Bsh[KC * LDB];            // [kk][px]

    const int Ktot     = CIN * K * K;
    const int npix_tot = BATCH * NSP;

    const int tid = threadIdx.x;
    const int px0 = blockIdx.x * TPX;
    const int co0 = blockIdx.y * TCO;
    const int tc  = tid & 15;
    const int tp  = tid >> 4;

    float acc[CO_T][PX_T];
#pragma unroll
    for (int i = 0; i < CO_T; ++i)
#pragma unroll
        for (int j = 0; j < PX_T; ++j) acc[i][j] = 0.f;

    for (int k0 = 0; k0 < Ktot; k0 += KC) {
        // ---- stage A (weights): TCO x KC, float4 global reads along k ----
        constexpr int A_ITERS = TCO * KC / (256 * 4);
#pragma unroll
        for (int it = 0; it < A_ITERS; ++it) {
            int idx = tid + it * 256;
            int co  = idx >> 3;               // 0..TCO-1
            int k4  = idx & 7;
            int k   = k0 + k4 * 4;
            float4 w4 = make_float4(0.f, 0.f, 0.f, 0.f);
            int cog = co0 + co;
            if (cog < COUT) {
                const float* wp = wgt + (size_t)cog * Ktot + k;
                if (k + 3 < Ktot) {
                    w4 = *(const float4*)wp;
                } else {
                    if (k + 0 < Ktot) w4.x = wp[0];
                    if (k + 1 < Ktot) w4.y = wp[1];
                    if (k + 2 < Ktot) w4.z = wp[2];
                    if (k + 3 < Ktot) w4.w = wp[3];
                }
            }
            Ash[(k4 * 4 + 0) * LDA + co] = w4.x;
            Ash[(k4 * 4 + 1) * LDA + co] = w4.y;
            Ash[(k4 * 4 + 2) * LDA + co] = w4.z;
            Ash[(k4 * 4 + 3) * LDA + co] = w4.w;
        }
        // ---- stage B (im2col gather): KC x TPX ----
        constexpr int B_ITERS = TPX * KC / 256;
#pragma unroll
        for (int it = 0; it < B_ITERS; ++it) {
            int idx = tid + it * 256;
            int px  = idx & (TPX - 1);
            int kk  = idx / TPX;
            int k   = k0 + kk;
            int p   = px0 + px;
            float v = 0.f;
            if (k < Ktot && p < npix_tot) {
                int ci = k / (K * K);
                int r  = k - ci * K * K;
                int kh = r / K;
                int kw = r - kh * K;
                int b  = p / NSP;
                int sp = p - b * NSP;
                int ho = sp / WOUT;
                int wo = sp - ho * WOUT;
                int hi = ho * STRIDE - PAD + kh;
                int wi = wo * STRIDE - PAD + kw;
                if (hi >= 0 && hi < WIN && wi >= 0 && wi < WIN)
                    v = in[((size_t)(b * CIN + ci) * WIN + hi) * WIN + wi];
            }
            Bsh[kk * LDB + px] = v;
        }
        __syncthreads();
        // ---- outer-product inner loop ----
#pragma unroll
        for (int kk = 0; kk < KC; ++kk) {
            float a[CO_T], bb[PX_T];
#pragma unroll
            for (int h = 0; h < CO_T / 4; ++h) {
                float4 f = *(const float4*)&Ash[kk * LDA + h * 64 + tc * 4];
                a[h*4+0] = f.x; a[h*4+1] = f.y; a[h*4+2] = f.z; a[h*4+3] = f.w;
            }
#pragma unroll
            for (int h = 0; h < PX_T / 4; ++h) {
                float4 f = *(const float4*)&Bsh[kk * LDB + h * 64 + tp * 4];
                bb[h*4+0] = f.x; bb[h*4+1] = f.y; bb[h*4+2] = f.z; bb[h*4+3] = f.w;
            }
#pragma unroll
            for (int i = 0; i < CO_T; ++i)
#pragma unroll
                for (int j = 0; j < PX_T; ++j)
                    acc[i][j] = fmaf(a[i], bb[j], acc[i][j]);
        }
        __syncthreads();
    }

    // ---- epilogue ----
#pragma unroll
    for (int i = 0; i < CO_T; ++i) {
        int co = co0 + (i >> 2) * 64 + tc * 4 + (i & 3);
        if (co >= COUT) continue;
        float bs = bias[co];
#pragma unroll
        for (int j = 0; j < PX_T; ++j) {
            int p = px0 + (j >> 2) * 64 + tp * 4 + (j & 3);
            if (p >= npix_tot) continue;
            int b  = p / NSP;
            int sp = p - b * NSP;
            float vv = acc[i][j] + bs;
            if (RELU) vv = fmaxf(vv, 0.f);
            out[((size_t)(b * COUT + co)) * NSP + sp] = vv;
        }
    }
}

// ---------------------------------------------------------------------------
// FC GEMM: out[m,n] = in[m,:] . w[n,:] + bias[n].  Tile 64n x 64m, chunk 32.
// ---------------------------------------------------------------------------
template<bool RELU>
__global__ __launch_bounds__(256, 4) void fc_gemm(
        const float* __restrict__ in, const float* __restrict__ w,
        const float* __restrict__ bias, float* __restrict__ out,
        int M, int N, int Kd) {
    constexpr int KC  = 32;
    constexpr int LDA = 68;
    __shared__ float Ash[KC * LDA];
    __shared__ float Bsh[KC * LDA];

    const int tid = threadIdx.x;
    const int n0 = blockIdx.x * 64;

    const int tn = tid & 15;
    const int tm = tid >> 4;

    float acc[4][4] = {{0.f}};

    for (int k0 = 0; k0 < Kd; k0 += KC) {
#pragma unroll
        for (int it = 0; it < 2; ++it) {
            int idx = tid + it * 256;
            int n   = idx >> 3;
            int k4  = idx & 7;
            int k   = k0 + k4 * 4;
            float4 w4 = make_float4(0.f, 0.f, 0.f, 0.f);
            int ng = n0 + n;
            if (ng < N) {
                const float* wp = w + (size_t)ng * Kd + k;
                if (k + 3 < Kd) {
                    w4 = *(const float4*)wp;
                } else {
                    if (k + 0 < Kd) w4.x = wp[0];
                    if (k + 1 < Kd) w4.y = wp[1];
                    if (k + 2 < Kd) w4.z = wp[2];
                    if (k + 3 < Kd) w4.w = wp[3];
                }
            }
            Ash[(k4 * 4 + 0) * LDA + n] = w4.x;
            Ash[(k4 * 4 + 1) * LDA + n] = w4.y;
            Ash[(k4 * 4 + 2) * LDA + n] = w4.z;
            Ash[(k4 * 4 + 3) * LDA + n] = w4.w;
        }
#pragma unroll
        for (int it = 0; it < 2; ++it) {
            int idx = tid + it * 256;
            int m   = idx >> 3;
            int k4  = idx & 7;
            int k   = k0 + k4 * 4;
            float4 x4 = make_float4(0.f, 0.f, 0.f, 0.f);
            if (m < M) {
                const float* xp = in + (size_t)m * Kd + k;
                if (k + 3 < Kd) {
                    x4 = *(const float4*)xp;
                } else {
                    if (k + 0 < Kd) x4.x = xp[0];
                    if (k + 1 < Kd) x4.y = xp[1];
                    if (k + 2 < Kd) x4.z = xp[2];
                    if (k + 3 < Kd) x4.w = xp[3];
                }
            }
            Bsh[(k4 * 4 + 0) * LDA + m] = x4.x;
            Bsh[(k4 * 4 + 1) * LDA + m] = x4.y;
            Bsh[(k4 * 4 + 2) * LDA + m] = x4.z;
            Bsh[(k4 * 4 + 3) * LDA + m] = x4.w;
        }
        __syncthreads();
#pragma unroll
        for (int kk = 0; kk < KC; ++kk) {
            float4 a4 = *(const float4*)&Ash[kk * LDA + tn * 4];
            float4 b4 = *(const float4*)&Bsh[kk * LDA + tm * 4];
            float av[4] = {a4.x, a4.y, a4.z, a4.w};
            float bv[4] = {b4.x, b4.y, b4.z, b4.w};
#pragma unroll
            for (int i = 0; i < 4; ++i)
#pragma unroll
                for (int j = 0; j < 4; ++j)
                    acc[i][j] = fmaf(av[i], bv[j], acc[i][j]);
        }
        __syncthreads();
    }

#pragma unroll
    for (int i = 0; i < 4; ++i) {
        int ng = n0 + tn * 4 + i;
        if (ng >= N) continue;
        float bs = bias[ng];
#pragma unroll
        for (int j = 0; j < 4; ++j) {
            int m = tm * 4 + j;
            if (m >= M) continue;
            float vv = acc[i][j] + bs;
            if (RELU) vv = fmaxf(vv, 0.f);
            out[(size_t)m * N + ng] = vv;
        }
    }
}

// ---------------- maxpool ---------------------------------------------------
__global__ void maxpool_k(const float* __restrict__ in, float* __restrict__ out,
                          int BC, int HIN, int WIN, int HOUT, int WOUT,
                          int KS, int S, int P) {
    int idx = blockIdx.x * blockDim.x + threadIdx.x;
    int total = BC * HOUT * WOUT;
    if (idx >= total) return;
    int wo = idx % WOUT;
    int ho = (idx / WOUT) % HOUT;
    int bc = idx / (WOUT * HOUT);
    int h0 = ho * S - P, w0 = wo * S - P;
    int h1 = h0 + KS, w1 = w0 + KS;
    if (h0 < 0) h0 = 0;
    if (w0 < 0) w0 = 0;
    if (h1 > HIN) h1 = HIN;
    if (w1 > WIN) w1 = WIN;
    const float* base = in + (size_t)bc * HIN * WIN;
    float m = -INFINITY;
    for (int h = h0; h < h1; h++)
        for (int w = w0; w < w1; w++)
            m = fmaxf(m, base[h * WIN + w]);
    out[idx] = m;
}

// ---------------- squash over trailing dim of 8 ----------------------------
__global__ void squash_u(const float* __restrict__ p, float* __restrict__ u, int ncaps) {
    int idx = blockIdx.x * blockDim.x + threadIdx.x;
    if (idx >= ncaps) return;
    const float4* pp = (const float4*)(p + (size_t)idx * 8);
    float4 a = pp[0], b = pp[1];
    float sq = a.x*a.x + a.y*a.y + a.z*a.z + a.w*a.w
             + b.x*b.x + b.y*b.y + b.z*b.z + b.w*b.w;
    float scale = (sq / (1.f + sq)) / sqrtf(sq + 1e-8f);
    float4* uu = (float4*)(u + (size_t)idx * 8);
    float4 oa, ob;
    oa.x = a.x*scale; oa.y = a.y*scale; oa.z = a.z*scale; oa.w = a.w*scale;
    ob.x = b.x*scale; ob.y = b.y*scale; ob.z = b.z*scale; ob.w = b.w*scale;
    uu[0] = oa; uu[1] = ob;
}

// ---------------- softmax over J (axis=1 of [B,J,I]) -----------------------
__global__ void softmax_j(const float* __restrict__ blog, float* __restrict__ c,
                          int Bn, int J, int I) {
    int idx = blockIdx.x * blockDim.x + threadIdx.x;
    if (idx >= Bn * I) return;
    int b = idx / I, i = idx - b * I;
    const float* base = blog + (size_t)b * J * I + i;
    float m = -INFINITY;
    for (int j = 0; j < J; j++) m = fmaxf(m, base[(size_t)j * I]);
    float* cb = c + (size_t)b * J * I + i;
    float sum = 0.f;
    for (int j = 0; j < J; j++) {
        float e = expf(base[(size_t)j * I] - m);
        sum += e;
        cb[(size_t)j * I] = e;
    }
    float inv = 1.f / sum;
    for (int j = 0; j < J; j++) cb[(size_t)j * I] *= inv;
}

// ===========================================================================
// Routing, LDS-staged-W (round 4).
// ===========================================================================
__device__ __forceinline__ void stage_W(const float* __restrict__ W,
                                        float* __restrict__ wsh,
                                        int j, int i0, int tid) {
    const float4* Wp = (const float4*)(W + ((size_t)j * NI + i0) * 128);
#pragma unroll
    for (int p = 0; p < 8; ++p) {
        int vi  = p * 256 + tid;
        int row = vi >> 5;
        int c4  = vi & 31;
        float4 f = Wp[vi];
        *(float4*)&wsh[row * LDW + c4 * 4] = f;
    }
}

__global__ __launch_bounds__(256) void route_s_w(
        const float* __restrict__ c, const float* __restrict__ u,
        const float* __restrict__ W, float* __restrict__ ppart, int uniform) {
    __shared__ float wsh[IC * LDW];
    const int tid = threadIdx.x;
    const int icb = blockIdx.x;
    const int j   = blockIdx.y;
    const int i0  = icb * IC;

    stage_W(W, wsh, j, i0, tid);
    __syncthreads();

    const int bg = tid >> 4;
    const int iq = tid & 15;
    const float invJ = 1.f / (float)NJ;

    float s[4][16];
#pragma unroll
    for (int bb = 0; bb < 4; ++bb)
#pragma unroll
        for (int o = 0; o < 16; ++o) s[bb][o] = 0.f;

#pragma unroll
    for (int k = 0; k < 4; ++k) {
        int il = iq + 16 * k;
        int ig = i0 + il;
        const float* wr = &wsh[il * LDW];
        float4 ua[4], ub[4];
        float cc[4];
#pragma unroll
        for (int bb = 0; bb < 4; ++bb) {
            int b = bg * 4 + bb;
            const float4* up = (const float4*)(u + ((size_t)b * NI + ig) * 8);
            ua[bb] = up[0];
            ub[bb] = up[1];
            cc[bb] = uniform ? invJ : c[((size_t)b * NJ + j) * NI + ig];
        }
#pragma unroll
        for (int o = 0; o < 16; ++o) {
            float4 w0 = *(const float4*)&wr[o * 8];
            float4 w1 = *(const float4*)&wr[o * 8 + 4];
#pragma unroll
            for (int bb = 0; bb < 4; ++bb) {
                float dot = w0.x*ua[bb].x + w0.y*ua[bb].y + w0.z*ua[bb].z + w0.w*ua[bb].w
                          + w1.x*ub[bb].x + w1.y*ub[bb].y + w1.z*ub[bb].z + w1.w*ub[bb].w;
                s[bb][o] = fmaf(cc[bb], dot, s[bb][o]);
            }
        }
    }

#pragma unroll
    for (int off = 8; off > 0; off >>= 1)
#pragma unroll
        for (int bb = 0; bb < 4; ++bb)
#pragma unroll
            for (int o = 0; o < 16; ++o)
                s[bb][o] += __shfl_down(s[bb][o], off, 16);

    if (iq == 0) {
#pragma unroll
        for (int bb = 0; bb < 4; ++bb) {
            int b = bg * 4 + bb;
            size_t base = ((size_t)icb * BJ + (size_t)b * NJ + j) * 16;
#pragma unroll
            for (int o4 = 0; o4 < 4; ++o4)
                *(float4*)&ppart[base + o4 * 4] =
                    make_float4(s[bb][o4*4+0], s[bb][o4*4+1], s[bb][o4*4+2], s[bb][o4*4+3]);
        }
    }
}

__global__ __launch_bounds__(64) void reduce_squash(
        const float* __restrict__ ppart, float* __restrict__ v) {
    int l = threadIdx.x >> 4;
    int o = threadIdx.x & 15;
    int bj = blockIdx.x * 4 + l;
    float s = 0.f;
    for (int ic = 0; ic < NIC; ic++)
        s += ppart[((size_t)ic * BJ + bj) * 16 + o];
    __shared__ float sarr[4][16];
    sarr[l][o] = s;
    __syncthreads();
    float ssq = 0.f;
#pragma unroll
    for (int k = 0; k < 16; k++) { float t = sarr[l][k]; ssq += t * t; }
    float scale = (ssq / (1.f + ssq)) / sqrtf(ssq + 1e-8f);
    v[(size_t)bj * 16 + o] = s * scale;
}

__global__ __launch_bounds__(256) void route_bupd_w(
        const float* __restrict__ u, const float* __restrict__ W,
        const float* __restrict__ v, float* __restrict__ blog, int accumulate) {
    __shared__ float wsh[IC * LDW];
    const int tid = threadIdx.x;
    const int icb = blockIdx.x;
    const int j   = blockIdx.y;
    const int i0  = icb * IC;

    stage_W(W, wsh, j, i0, tid);
    __syncthreads();

    const int bg = tid >> 4;
    const int iq = tid & 15;

    float vv[4][16];
#pragma unroll
    for (int bb = 0; bb < 4; ++bb) {
        int b = bg * 4 + bb;
        const float4* vp = (const float4*)(v + ((size_t)b * NJ + j) * 16);
#pragma unroll
        for (int o4 = 0; o4 < 4; ++o4) {
            float4 f = vp[o4];
            vv[bb][o4*4+0] = f.x; vv[bb][o4*4+1] = f.y;
            vv[bb][o4*4+2] = f.z; vv[bb][o4*4+3] = f.w;
        }
    }

#pragma unroll
    for (int k = 0; k < 4; ++k) {
        int il = iq + 16 * k;
        int ig = i0 + il;
        const float* wr = &wsh[il * LDW];
        float4 ua[4], ub[4];
#pragma unroll
        for (int bb = 0; bb < 4; ++bb) {
            int b = bg * 4 + bb;
            const float4* up = (const float4*)(u + ((size_t)b * NI + ig) * 8);
            ua[bb] = up[0];
            ub[bb] = up[1];
        }
        float acc[4] = {0.f, 0.f, 0.f, 0.f};
#pragma unroll
        for (int o = 0; o < 16; ++o) {
            float4 w0 = *(const float4*)&wr[o * 8];
            float4 w1 = *(const float4*)&wr[o * 8 + 4];
#pragma unroll
            for (int bb = 0; bb < 4; ++bb) {
                float dot = w0.x*ua[bb].x + w0.y*ua[bb].y + w0.z*ua[bb].z + w0.w*ua[bb].w
                          + w1.x*ub[bb].x + w1.y*ub[bb].y + w1.z*ub[bb].z + w1.w*ub[bb].w;
                acc[bb] = fmaf(vv[bb][o], dot, acc[bb]);
            }
        }
#pragma unroll
        for (int bb = 0; bb < 4; ++bb) {
            int b = bg * 4 + bb;
            size_t idx = ((size_t)b * NJ + j) * NI + ig;
            blog[idx] = accumulate ? (blog[idx] + acc[bb]) : acc[bb];
        }
    }
}

// ---------------------------------------------------------------------------
extern "C" void kernel_launch(void* const* d_in, const int* in_sizes, int n_in,
                              void* d_out, int out_size, void* d_ws, size_t ws_size,
                              hipStream_t stream) {
    const float* x     = (const float*)d_in[0];
    const float* w1    = (const float*)d_in[1];
    const float* b1    = (const float*)d_in[2];
    const float* w2    = (const float*)d_in[3];
    const float* b2    = (const float*)d_in[4];
    const float* w3    = (const float*)d_in[5];
    const float* b3    = (const float*)d_in[6];
    const float* w4    = (const float*)d_in[7];
    const float* b4    = (const float*)d_in[8];
    const float* w5    = (const float*)d_in[9];
    const float* b5    = (const float*)d_in[10];
    const float* pc_w  = (const float*)d_in[11];
    const float* pc_b  = (const float*)d_in[12];
    const float* capsW = (const float*)d_in[13];
    const float* fc1_w = (const float*)d_in[14];
    const float* fc1_b = (const float*)d_in[15];
    const float* fc2_w = (const float*)d_in[16];
    const float* fc2_b = (const float*)d_in[17];
    const float* fc3_w = (const float*)d_in[18];
    const float* fc3_b = (const float*)d_in[19];
    float* outp = (float*)d_out;

    // ws layout: A (80 MB) | Bb (20 MB) | Dd (4 MB)
    char* ws = (char*)d_ws;
    float* A  = (float*)ws;
    float* Bb = (float*)(ws + ((size_t)80 << 20));
    float* Dd = (float*)(ws + ((size_t)100 << 20));
    float* blog  = A;                        // [64,101,1152]
    float* csm   = A + 7446528;              // [64,101,1152]
    float* ppart = A + 2 * 7446528;          // [18][6464][16]
    float* vcap = Dd;                        // [64,101,16]
    float* f1   = Dd + 131072;
    float* f2   = Dd + 131072 + 262144;

    const int B = BATCH;

    // ---- conv stack (batch-folded implicit GEMM) ----
    // conv1: [64,3,227,227] -> [64,96,55,55], px_tot = 193600
    conv_igemm2<11, 4, 0, 55, true, 128, 128><<<dim3(1513, 1), dim3(256), 0, stream>>>(
        x, w1, b1, A, 3, 96, 227);
    maxpool_k<<<dim3(ceil_div(B * 96 * 27 * 27, 256)), dim3(256), 0, stream>>>(
        A, Bb, B * 96, 55, 55, 27, 27, 3, 2, 0);
    // conv2: [64,96,27,27] -> [64,256,27,27], px_tot = 46656
    conv_igemm2<5, 1, 2, 27, true, 128, 128><<<dim3(365, 2), dim3(256), 0, stream>>>(
        Bb, w2, b2, A, 96, 256, 27);
    maxpool_k<<<dim3(ceil_div(B * 256 * 14 * 14, 256)), dim3(256), 0, stream>>>(
        A, Bb, B * 256, 27, 27, 14, 14, 3, 2, 1);
    // conv3: [64,256,14,14] -> [64,384,14,14], px_tot = 12544
    conv_igemm2<3, 1, 1, 14, true, 64, 128><<<dim3(98, 6), dim3(256), 0, stream>>>(
        Bb, w3, b3, A, 256, 384, 14);
    // conv4
    conv_igemm2<3, 1, 1, 14, true, 64, 128><<<dim3(98, 6), dim3(256), 0, stream>>>(
        A, w4, b4, Bb, 384, 384, 14);
    // conv5
    conv_igemm2<3, 1, 1, 14, true, 64, 128><<<dim3(98, 4), dim3(256), 0, stream>>>(
        Bb, w5, b5, A, 384, 256, 14);
    maxpool_k<<<dim3(ceil_div(B * 256 * 6 * 6, 256)), dim3(256), 0, stream>>>(
        A, Bb, B * 256, 14, 14, 6, 6, 3, 2, 0);
    // primarycaps conv: [64,256,6,6] -> [64,256,6,6], px_tot = 2304
    conv_igemm2<3, 1, 1, 6, false, 64, 64><<<dim3(36, 4), dim3(256), 0, stream>>>(
        Bb, pc_w, pc_b, A, 256, 256, 6);
    squash_u<<<dim3(ceil_div(B * 1152, 256)), dim3(256), 0, stream>>>(A, Bb, B * 1152);
    // u now in Bb [64,1152,8]

    // ---- dynamic routing (3 iters), W staged in LDS ----
    dim3 rgrid(NIC, NJ);
    route_s_w<<<rgrid, dim3(256), 0, stream>>>(csm, Bb, capsW, ppart, 1);
    reduce_squash<<<dim3(BJ / 4), dim3(64), 0, stream>>>(ppart, vcap);
    route_bupd_w<<<rgrid, dim3(256), 0, stream>>>(Bb, capsW, vcap, blog, 0);
    softmax_j<<<dim3(ceil_div(B * NI, 256)), dim3(256), 0, stream>>>(
        blog, csm, B, NJ, NI);
    route_s_w<<<rgrid, dim3(256), 0, stream>>>(csm, Bb, capsW, ppart, 0);
    reduce_squash<<<dim3(BJ / 4), dim3(64), 0, stream>>>(ppart, vcap);
    route_bupd_w<<<rgrid, dim3(256), 0, stream>>>(Bb, capsW, vcap, blog, 1);
    softmax_j<<<dim3(ceil_div(B * NI, 256)), dim3(256), 0, stream>>>(
        blog, csm, B, NJ, NI);
    route_s_w<<<rgrid, dim3(256), 0, stream>>>(csm, Bb, capsW, ppart, 0);
    reduce_squash<<<dim3(BJ / 4), dim3(64), 0, stream>>>(ppart, vcap);

    // ---- MLP head ----
    fc_gemm<true><<<dim3(64), dim3(256), 0, stream>>>(vcap, fc1_w, fc1_b, f1, B, 4096, 1616);
    fc_gemm<true><<<dim3(64), dim3(256), 0, stream>>>(f1, fc2_w, fc2_b, f2, B, 4096, 4096);
    fc_gemm<false><<<dim3(2), dim3(256), 0, stream>>>(f2, fc3_w, fc3_b, outp, B, 101, 4096);
}

// Round 6
// 5788.473 us; speedup vs baseline: 1.2365x; 1.2365x over previous
//
#include <hip/hip_runtime.h>
#include <math.h>

// ---------------------------------------------------------------------------
// AlexCapsNet (FOOD101) forward. Round 6: implicit-GEMM convs, 64x64 tile
// (occupancy 4), batch-folded grid, hoisted per-thread pixel math (fixed-px
// staging roles) + register-prefetch double buffering. Routing: LDS-staged W.
// ---------------------------------------------------------------------------

#define BATCH 64
#define NJ 101
#define NI 1152
#define BJ (BATCH * NJ)          // 6464
#define IC 64                    // routing i-chunk per block
#define NIC (NI / IC)            // 18
#define LDW 132                  // routing LDS row stride (words)

static inline int ceil_div(int a, int b) { return (a + b - 1) / b; }

// ---------------------------------------------------------------------------
// Implicit-GEMM conv, batch folded into pixel dim, 64co x 64px tile, KC=32.
// Staging roles: B-gather thread owns fixed px set {spx+8e}, k row varies;
// per-thread pixel math hoisted out of the chunk loop. Register prefetch of
// chunk c+1 overlaps gather latency with chunk c compute.
// All pixel tiles are exact (npix_tot % 64 == 0 for every conv here).
// ---------------------------------------------------------------------------
template<int K, int STRIDE, int PAD, int WOUT, bool RELU>
__global__ __launch_bounds__(256, 4) void conv_igemm3(
        const float* __restrict__ in, const float* __restrict__ wgt,
        const float* __restrict__ bias, float* __restrict__ out,
        int CIN, int COUT, int WIN) {
    constexpr int KC  = 32;
    constexpr int KK  = K * K;
    constexpr int NSP = WOUT * WOUT;
    constexpr int LDA = 68;
    constexpr int LDB = 68;
    __shared__ float Ash[KC * LDA];   // [kk][co]
    __shared__ float Bsh[KC * LDB];   // [kk][px]

    const int Ktot  = CIN * KK;
    const int WINSQ = WIN * WIN;

    const int tid = threadIdx.x;
    const int px0 = blockIdx.x * 64;
    const int co0 = blockIdx.y * 64;
    const int tc  = tid & 15;
    const int tp  = tid >> 4;

    // ---- B-gather roles: k row = tid>>3 (32 rows), px = (tid&7) + 8e ----
    const int skk = tid >> 3;
    const int spx = tid & 7;

    // hoisted per-thread pixel math (fixed for the whole kernel)
    int baseB[8], hiB[8], wiB[8];
#pragma unroll
    for (int e = 0; e < 8; ++e) {
        int p  = px0 + spx + 8 * e;
        int b  = p / NSP;
        int sp = p - b * NSP;
        int ho = sp / WOUT;
        int wo = sp - ho * WOUT;
        hiB[e] = ho * STRIDE - PAD;
        wiB[e] = wo * STRIDE - PAD;
        baseB[e] = (b * CIN) * WINSQ + hiB[e] * WIN + wiB[e];
    }

    // ---- A-gather roles: co = (tid>>3) + 32*it, k = k0 + (tid&7)*4 ----
    const int aco = tid >> 3;
    const int ak4 = tid & 7;

    float4 pa[2];
    float  pv[8];

    auto gatherA = [&](int k0) {
#pragma unroll
        for (int it = 0; it < 2; ++it) {
            int co  = aco + it * 32;
            int k   = k0 + ak4 * 4;
            int cog = co0 + co;
            float4 w4 = make_float4(0.f, 0.f, 0.f, 0.f);
            if (cog < COUT) {
                const float* wp = wgt + (size_t)cog * Ktot + k;
                if (k + 3 < Ktot) {
                    w4 = *(const float4*)wp;
                } else {
                    if (k + 0 < Ktot) w4.x = wp[0];
                    if (k + 1 < Ktot) w4.y = wp[1];
                    if (k + 2 < Ktot) w4.z = wp[2];
                    if (k + 3 < Ktot) w4.w = wp[3];
                }
            }
            pa[it] = w4;
        }
    };

    auto gatherB = [&](int k0) {
        int k  = k0 + skk;
        int ci = k / KK;
        int r  = k - ci * KK;
        int kh = r / K;
        int kw = r - kh * K;
        int Aoff = ci * WINSQ + kh * WIN + kw;
        bool kok = (k < Ktot);
#pragma unroll
        for (int e = 0; e < 8; ++e) {
            bool ok = kok;
            if (PAD > 0) {
                int hi = hiB[e] + kh;
                int wi = wiB[e] + kw;
                ok = ok && ((unsigned)hi < (unsigned)WIN)
                        && ((unsigned)wi < (unsigned)WIN);
            }
            float v = 0.f;
            if (ok) v = in[baseB[e] + Aoff];
            pv[e] = v;
        }
    };

    float acc[4][4] = {{0.f}};

    gatherA(0);
    gatherB(0);
    const int nchunks = (Ktot + KC - 1) / KC;

    for (int c = 0; c < nchunks; ++c) {
        // ---- commit prefetched chunk to LDS ----
#pragma unroll
        for (int it = 0; it < 2; ++it) {
            int co = aco + it * 32;
            Ash[(ak4 * 4 + 0) * LDA + co] = pa[it].x;
            Ash[(ak4 * 4 + 1) * LDA + co] = pa[it].y;
            Ash[(ak4 * 4 + 2) * LDA + co] = pa[it].z;
            Ash[(ak4 * 4 + 3) * LDA + co] = pa[it].w;
        }
#pragma unroll
        for (int e = 0; e < 8; ++e)
            Bsh[skk * LDB + spx + 8 * e] = pv[e];
        __syncthreads();

        // ---- prefetch next chunk (loads overlap compute below) ----
        if (c + 1 < nchunks) {
            gatherA((c + 1) * KC);
            gatherB((c + 1) * KC);
        }

        // ---- inner product over the chunk ----
#pragma unroll
        for (int kk = 0; kk < KC; ++kk) {
            float4 a4 = *(const float4*)&Ash[kk * LDA + tc * 4];
            float4 b4 = *(const float4*)&Bsh[kk * LDB + tp * 4];
            float av[4] = {a4.x, a4.y, a4.z, a4.w};
            float bv[4] = {b4.x, b4.y, b4.z, b4.w};
#pragma unroll
            for (int i = 0; i < 4; ++i)
#pragma unroll
                for (int j = 0; j < 4; ++j)
                    acc[i][j] = fmaf(av[i], bv[j], acc[i][j]);
        }
        __syncthreads();
    }

    // ---- epilogue (pixel tiles are exact; only co can overflow) ----
#pragma unroll
    for (int i = 0; i < 4; ++i) {
        int co = co0 + tc * 4 + i;
        if (co >= COUT) continue;
        float bs = bias[co];
#pragma unroll
        for (int j = 0; j < 4; ++j) {
            int p  = px0 + tp * 4 + j;
            int b  = p / NSP;
            int sp = p - b * NSP;
            float vv = acc[i][j] + bs;
            if (RELU) vv = fmaxf(vv, 0.f);
            out[((size_t)(b * COUT + co)) * NSP + sp] = vv;
        }
    }
}

// ---------------------------------------------------------------------------
// FC GEMM: out[m,n] = in[m,:] . w[n,:] + bias[n].  Tile 64n x 64m, chunk 32.
// ---------------------------------------------------------------------------
template<bool RELU>
__global__ __launch_bounds__(256, 4) void fc_gemm(
        const float* __restrict__ in, const float* __restrict__ w,
        const float* __restrict__ bias, float* __restrict__ out,
        int M, int N, int Kd) {
    constexpr int KC  = 32;
    constexpr int LDA = 68;
    __shared__ float Ash[KC * LDA];
    __shared__ float Bsh[KC * LDA];

    const int tid = threadIdx.x;
    const int n0 = blockIdx.x * 64;

    const int tn = tid & 15;
    const int tm = tid >> 4;

    float acc[4][4] = {{0.f}};

    for (int k0 = 0; k0 < Kd; k0 += KC) {
#pragma unroll
        for (int it = 0; it < 2; ++it) {
            int idx = tid + it * 256;
            int n   = idx >> 3;
            int k4  = idx & 7;
            int k   = k0 + k4 * 4;
            float4 w4 = make_float4(0.f, 0.f, 0.f, 0.f);
            int ng = n0 + n;
            if (ng < N) {
                const float* wp = w + (size_t)ng * Kd + k;
                if (k + 3 < Kd) {
                    w4 = *(const float4*)wp;
                } else {
                    if (k + 0 < Kd) w4.x = wp[0];
                    if (k + 1 < Kd) w4.y = wp[1];
                    if (k + 2 < Kd) w4.z = wp[2];
                    if (k + 3 < Kd) w4.w = wp[3];
                }
            }
            Ash[(k4 * 4 + 0) * LDA + n] = w4.x;
            Ash[(k4 * 4 + 1) * LDA + n] = w4.y;
            Ash[(k4 * 4 + 2) * LDA + n] = w4.z;
            Ash[(k4 * 4 + 3) * LDA + n] = w4.w;
        }
#pragma unroll
        for (int it = 0; it < 2; ++it) {
            int idx = tid + it * 256;
            int m   = idx >> 3;
            int k4  = idx & 7;
            int k   = k0 + k4 * 4;
            float4 x4 = make_float4(0.f, 0.f, 0.f, 0.f);
            if (m < M) {
                const float* xp = in + (size_t)m * Kd + k;
                if (k + 3 < Kd) {
                    x4 = *(const float4*)xp;
                } else {
                    if (k + 0 < Kd) x4.x = xp[0];
                    if (k + 1 < Kd) x4.y = xp[1];
                    if (k + 2 < Kd) x4.z = xp[2];
                    if (k + 3 < Kd) x4.w = xp[3];
                }
            }
            Bsh[(k4 * 4 + 0) * LDA + m] = x4.x;
            Bsh[(k4 * 4 + 1) * LDA + m] = x4.y;
            Bsh[(k4 * 4 + 2) * LDA + m] = x4.z;
            Bsh[(k4 * 4 + 3) * LDA + m] = x4.w;
        }
        __syncthreads();
#pragma unroll
        for (int kk = 0; kk < KC; ++kk) {
            float4 a4 = *(const float4*)&Ash[kk * LDA + tn * 4];
            float4 b4 = *(const float4*)&Bsh[kk * LDA + tm * 4];
            float av[4] = {a4.x, a4.y, a4.z, a4.w};
            float bv[4] = {b4.x, b4.y, b4.z, b4.w};
#pragma unroll
            for (int i = 0; i < 4; ++i)
#pragma unroll
                for (int j = 0; j < 4; ++j)
                    acc[i][j] = fmaf(av[i], bv[j], acc[i][j]);
        }
        __syncthreads();
    }

#pragma unroll
    for (int i = 0; i < 4; ++i) {
        int ng = n0 + tn * 4 + i;
        if (ng >= N) continue;
        float bs = bias[ng];
#pragma unroll
        for (int j = 0; j < 4; ++j) {
            int m = tm * 4 + j;
            if (m >= M) continue;
            float vv = acc[i][j] + bs;
            if (RELU) vv = fmaxf(vv, 0.f);
            out[(size_t)m * N + ng] = vv;
        }
    }
}

// ---------------- maxpool ---------------------------------------------------
__global__ void maxpool_k(const float* __restrict__ in, float* __restrict__ out,
                          int BC, int HIN, int WIN, int HOUT, int WOUT,
                          int KS, int S, int P) {
    int idx = blockIdx.x * blockDim.x + threadIdx.x;
    int total = BC * HOUT * WOUT;
    if (idx >= total) return;
    int wo = idx % WOUT;
    int ho = (idx / WOUT) % HOUT;
    int bc = idx / (WOUT * HOUT);
    int h0 = ho * S - P, w0 = wo * S - P;
    int h1 = h0 + KS, w1 = w0 + KS;
    if (h0 < 0) h0 = 0;
    if (w0 < 0) w0 = 0;
    if (h1 > HIN) h1 = HIN;
    if (w1 > WIN) w1 = WIN;
    const float* base = in + (size_t)bc * HIN * WIN;
    float m = -INFINITY;
    for (int h = h0; h < h1; h++)
        for (int w = w0; w < w1; w++)
            m = fmaxf(m, base[h * WIN + w]);
    out[idx] = m;
}

// ---------------- squash over trailing dim of 8 ----------------------------
__global__ void squash_u(const float* __restrict__ p, float* __restrict__ u, int ncaps) {
    int idx = blockIdx.x * blockDim.x + threadIdx.x;
    if (idx >= ncaps) return;
    const float4* pp = (const float4*)(p + (size_t)idx * 8);
    float4 a = pp[0], b = pp[1];
    float sq = a.x*a.x + a.y*a.y + a.z*a.z + a.w*a.w
             + b.x*b.x + b.y*b.y + b.z*b.z + b.w*b.w;
    float scale = (sq / (1.f + sq)) / sqrtf(sq + 1e-8f);
    float4* uu = (float4*)(u + (size_t)idx * 8);
    float4 oa, ob;
    oa.x = a.x*scale; oa.y = a.y*scale; oa.z = a.z*scale; oa.w = a.w*scale;
    ob.x = b.x*scale; ob.y = b.y*scale; ob.z = b.z*scale; ob.w = b.w*scale;
    uu[0] = oa; uu[1] = ob;
}

// ---------------- softmax over J (axis=1 of [B,J,I]) -----------------------
__global__ void softmax_j(const float* __restrict__ blog, float* __restrict__ c,
                          int Bn, int J, int I) {
    int idx = blockIdx.x * blockDim.x + threadIdx.x;
    if (idx >= Bn * I) return;
    int b = idx / I, i = idx - b * I;
    const float* base = blog + (size_t)b * J * I + i;
    float m = -INFINITY;
    for (int j = 0; j < J; j++) m = fmaxf(m, base[(size_t)j * I]);
    float* cb = c + (size_t)b * J * I + i;
    float sum = 0.f;
    for (int j = 0; j < J; j++) {
        float e = expf(base[(size_t)j * I] - m);
        sum += e;
        cb[(size_t)j * I] = e;
    }
    float inv = 1.f / sum;
    for (int j = 0; j < J; j++) cb[(size_t)j * I] *= inv;
}

// ===========================================================================
// Routing, LDS-staged-W (round 4, proven).
// ===========================================================================
__device__ __forceinline__ void stage_W(const float* __restrict__ W,
                                        float* __restrict__ wsh,
                                        int j, int i0, int tid) {
    const float4* Wp = (const float4*)(W + ((size_t)j * NI + i0) * 128);
#pragma unroll
    for (int p = 0; p < 8; ++p) {
        int vi  = p * 256 + tid;
        int row = vi >> 5;
        int c4  = vi & 31;
        float4 f = Wp[vi];
        *(float4*)&wsh[row * LDW + c4 * 4] = f;
    }
}

__global__ __launch_bounds__(256) void route_s_w(
        const float* __restrict__ c, const float* __restrict__ u,
        const float* __restrict__ W, float* __restrict__ ppart, int uniform) {
    __shared__ float wsh[IC * LDW];
    const int tid = threadIdx.x;
    const int icb = blockIdx.x;
    const int j   = blockIdx.y;
    const int i0  = icb * IC;

    stage_W(W, wsh, j, i0, tid);
    __syncthreads();

    const int bg = tid >> 4;
    const int iq = tid & 15;
    const float invJ = 1.f / (float)NJ;

    float s[4][16];
#pragma unroll
    for (int bb = 0; bb < 4; ++bb)
#pragma unroll
        for (int o = 0; o < 16; ++o) s[bb][o] = 0.f;

#pragma unroll
    for (int k = 0; k < 4; ++k) {
        int il = iq + 16 * k;
        int ig = i0 + il;
        const float* wr = &wsh[il * LDW];
        float4 ua[4], ub[4];
        float cc[4];
#pragma unroll
        for (int bb = 0; bb < 4; ++bb) {
            int b = bg * 4 + bb;
            const float4* up = (const float4*)(u + ((size_t)b * NI + ig) * 8);
            ua[bb] = up[0];
            ub[bb] = up[1];
            cc[bb] = uniform ? invJ : c[((size_t)b * NJ + j) * NI + ig];
        }
#pragma unroll
        for (int o = 0; o < 16; ++o) {
            float4 w0 = *(const float4*)&wr[o * 8];
            float4 w1 = *(const float4*)&wr[o * 8 + 4];
#pragma unroll
            for (int bb = 0; bb < 4; ++bb) {
                float dot = w0.x*ua[bb].x + w0.y*ua[bb].y + w0.z*ua[bb].z + w0.w*ua[bb].w
                          + w1.x*ub[bb].x + w1.y*ub[bb].y + w1.z*ub[bb].z + w1.w*ub[bb].w;
                s[bb][o] = fmaf(cc[bb], dot, s[bb][o]);
            }
        }
    }

#pragma unroll
    for (int off = 8; off > 0; off >>= 1)
#pragma unroll
        for (int bb = 0; bb < 4; ++bb)
#pragma unroll
            for (int o = 0; o < 16; ++o)
                s[bb][o] += __shfl_down(s[bb][o], off, 16);

    if (iq == 0) {
#pragma unroll
        for (int bb = 0; bb < 4; ++bb) {
            int b = bg * 4 + bb;
            size_t base = ((size_t)icb * BJ + (size_t)b * NJ + j) * 16;
#pragma unroll
            for (int o4 = 0; o4 < 4; ++o4)
                *(float4*)&ppart[base + o4 * 4] =
                    make_float4(s[bb][o4*4+0], s[bb][o4*4+1], s[bb][o4*4+2], s[bb][o4*4+3]);
        }
    }
}

__global__ __launch_bounds__(64) void reduce_squash(
        const float* __restrict__ ppart, float* __restrict__ v) {
    int l = threadIdx.x >> 4;
    int o = threadIdx.x & 15;
    int bj = blockIdx.x * 4 + l;
    float s = 0.f;
    for (int ic = 0; ic < NIC; ic++)
        s += ppart[((size_t)ic * BJ + bj) * 16 + o];
    __shared__ float sarr[4][16];
    sarr[l][o] = s;
    __syncthreads();
    float ssq = 0.f;
#pragma unroll
    for (int k = 0; k < 16; k++) { float t = sarr[l][k]; ssq += t * t; }
    float scale = (ssq / (1.f + ssq)) / sqrtf(ssq + 1e-8f);
    v[(size_t)bj * 16 + o] = s * scale;
}

__global__ __launch_bounds__(256) void route_bupd_w(
        const float* __restrict__ u, const float* __restrict__ W,
        const float* __restrict__ v, float* __restrict__ blog, int accumulate) {
    __shared__ float wsh[IC * LDW];
    const int tid = threadIdx.x;
    const int icb = blockIdx.x;
    const int j   = blockIdx.y;
    const int i0  = icb * IC;

    stage_W(W, wsh, j, i0, tid);
    __syncthreads();

    const int bg = tid >> 4;
    const int iq = tid & 15;

    float vv[4][16];
#pragma unroll
    for (int bb = 0; bb < 4; ++bb) {
        int b = bg * 4 + bb;
        const float4* vp = (const float4*)(v + ((size_t)b * NJ + j) * 16);
#pragma unroll
        for (int o4 = 0; o4 < 4; ++o4) {
            float4 f = vp[o4];
            vv[bb][o4*4+0] = f.x; vv[bb][o4*4+1] = f.y;
            vv[bb][o4*4+2] = f.z; vv[bb][o4*4+3] = f.w;
        }
    }

#pragma unroll
    for (int k = 0; k < 4; ++k) {
        int il = iq + 16 * k;
        int ig = i0 + il;
        const float* wr = &wsh[il * LDW];
        float4 ua[4], ub[4];
#pragma unroll
        for (int bb = 0; bb < 4; ++bb) {
            int b = bg * 4 + bb;
            const float4* up = (const float4*)(u + ((size_t)b * NI + ig) * 8);
            ua[bb] = up[0];
            ub[bb] = up[1];
        }
        float acc[4] = {0.f, 0.f, 0.f, 0.f};
#pragma unroll
        for (int o = 0; o < 16; ++o) {
            float4 w0 = *(const float4*)&wr[o * 8];
            float4 w1 = *(const float4*)&wr[o * 8 + 4];
#pragma unroll
            for (int bb = 0; bb < 4; ++bb) {
                float dot = w0.x*ua[bb].x + w0.y*ua[bb].y + w0.z*ua[bb].z + w0.w*ua[bb].w
                          + w1.x*ub[bb].x + w1.y*ub[bb].y + w1.z*ub[bb].z + w1.w*ub[bb].w;
                acc[bb] = fmaf(vv[bb][o], dot, acc[bb]);
            }
        }
#pragma unroll
        for (int bb = 0; bb < 4; ++bb) {
            int b = bg * 4 + bb;
            size_t idx = ((size_t)b * NJ + j) * NI + ig;
            blog[idx] = accumulate ? (blog[idx] + acc[bb]) : acc[bb];
        }
    }
}

// ---------------------------------------------------------------------------
extern "C" void kernel_launch(void* const* d_in, const int* in_sizes, int n_in,
                              void* d_out, int out_size, void* d_ws, size_t ws_size,
                              hipStream_t stream) {
    const float* x     = (const float*)d_in[0];
    const float* w1    = (const float*)d_in[1];
    const float* b1    = (const float*)d_in[2];
    const float* w2    = (const float*)d_in[3];
    const float* b2    = (const float*)d_in[4];
    const float* w3    = (const float*)d_in[5];
    const float* b3    = (const float*)d_in[6];
    const float* w4    = (const float*)d_in[7];
    const float* b4    = (const float*)d_in[8];
    const float* w5    = (const float*)d_in[9];
    const float* b5    = (const float*)d_in[10];
    const float* pc_w  = (const float*)d_in[11];
    const float* pc_b  = (const float*)d_in[12];
    const float* capsW = (const float*)d_in[13];
    const float* fc1_w = (const float*)d_in[14];
    const float* fc1_b = (const float*)d_in[15];
    const float* fc2_w = (const float*)d_in[16];
    const float* fc2_b = (const float*)d_in[17];
    const float* fc3_w = (const float*)d_in[18];
    const float* fc3_b = (const float*)d_in[19];
    float* outp = (float*)d_out;

    // ws layout: A (80 MB) | Bb (20 MB) | Dd (4 MB)
    char* ws = (char*)d_ws;
    float* A  = (float*)ws;
    float* Bb = (float*)(ws + ((size_t)80 << 20));
    float* Dd = (float*)(ws + ((size_t)100 << 20));
    float* blog  = A;                        // [64,101,1152]
    float* csm   = A + 7446528;              // [64,101,1152]
    float* ppart = A + 2 * 7446528;          // [18][6464][16]
    float* vcap = Dd;                        // [64,101,16]
    float* f1   = Dd + 131072;
    float* f2   = Dd + 131072 + 262144;

    const int B = BATCH;

    // ---- conv stack (batch-folded, 64x64 tiles, prefetch) ----
    // conv1: [64,3,227,227] -> [64,96,55,55], px_tot = 193600 = 3025*64
    conv_igemm3<11, 4, 0, 55, true><<<dim3(3025, 2), dim3(256), 0, stream>>>(
        x, w1, b1, A, 3, 96, 227);
    maxpool_k<<<dim3(ceil_div(B * 96 * 27 * 27, 256)), dim3(256), 0, stream>>>(
        A, Bb, B * 96, 55, 55, 27, 27, 3, 2, 0);
    // conv2: [64,96,27,27] -> [64,256,27,27], px_tot = 46656 = 729*64
    conv_igemm3<5, 1, 2, 27, true><<<dim3(729, 4), dim3(256), 0, stream>>>(
        Bb, w2, b2, A, 96, 256, 27);
    maxpool_k<<<dim3(ceil_div(B * 256 * 14 * 14, 256)), dim3(256), 0, stream>>>(
        A, Bb, B * 256, 27, 27, 14, 14, 3, 2, 1);
    // conv3: [64,256,14,14] -> [64,384,14,14], px_tot = 12544 = 196*64
    conv_igemm3<3, 1, 1, 14, true><<<dim3(196, 6), dim3(256), 0, stream>>>(
        Bb, w3, b3, A, 256, 384, 14);
    // conv4
    conv_igemm3<3, 1, 1, 14, true><<<dim3(196, 6), dim3(256), 0, stream>>>(
        A, w4, b4, Bb, 384, 384, 14);
    // conv5
    conv_igemm3<3, 1, 1, 14, true><<<dim3(196, 4), dim3(256), 0, stream>>>(
        Bb, w5, b5, A, 384, 256, 14);
    maxpool_k<<<dim3(ceil_div(B * 256 * 6 * 6, 256)), dim3(256), 0, stream>>>(
        A, Bb, B * 256, 14, 14, 6, 6, 3, 2, 0);
    // primarycaps conv: [64,256,6,6] -> [64,256,6,6], px_tot = 2304 = 36*64
    conv_igemm3<3, 1, 1, 6, false><<<dim3(36, 4), dim3(256), 0, stream>>>(
        Bb, pc_w, pc_b, A, 256, 256, 6);
    squash_u<<<dim3(ceil_div(B * 1152, 256)), dim3(256), 0, stream>>>(A, Bb, B * 1152);
    // u now in Bb [64,1152,8]

    // ---- dynamic routing (3 iters), W staged in LDS ----
    dim3 rgrid(NIC, NJ);
    route_s_w<<<rgrid, dim3(256), 0, stream>>>(csm, Bb, capsW, ppart, 1);
    reduce_squash<<<dim3(BJ / 4), dim3(64), 0, stream>>>(ppart, vcap);
    route_bupd_w<<<rgrid, dim3(256), 0, stream>>>(Bb, capsW, vcap, blog, 0);
    softmax_j<<<dim3(ceil_div(B * NI, 256)), dim3(256), 0, stream>>>(
        blog, csm, B, NJ, NI);
    route_s_w<<<rgrid, dim3(256), 0, stream>>>(csm, Bb, capsW, ppart, 0);
    reduce_squash<<<dim3(BJ / 4), dim3(64), 0, stream>>>(ppart, vcap);
    route_bupd_w<<<rgrid, dim3(256), 0, stream>>>(Bb, capsW, vcap, blog, 1);
    softmax_j<<<dim3(ceil_div(B * NI, 256)), dim3(256), 0, stream>>>(
        blog, csm, B, NJ, NI);
    route_s_w<<<rgrid, dim3(256), 0, stream>>>(csm, Bb, capsW, ppart, 0);
    reduce_squash<<<dim3(BJ / 4), dim3(64), 0, stream>>>(ppart, vcap);

    // ---- MLP head ----
    fc_gemm<true><<<dim3(64), dim3(256), 0, stream>>>(vcap, fc1_w, fc1_b, f1, B, 4096, 1616);
    fc_gemm<true><<<dim3(64), dim3(256), 0, stream>>>(f1, fc2_w, fc2_b, f2, B, 4096, 4096);
    fc_gemm<false><<<dim3(2), dim3(256), 0, stream>>>(f2, fc3_w, fc3_b, outp, B, 101, 4096);
}

// Round 7
// 3917.784 us; speedup vs baseline: 1.8268x; 1.4775x over previous
//
#include <hip/hip_runtime.h>
#include <math.h>

// ---------------------------------------------------------------------------
// AlexCapsNet (FOOD101) forward. Round 7: bf16x3-split MFMA implicit-GEMM
// convs (fp32-accurate via hi/lo decomposition, 3 MFMAs per logical product).
// Routing: LDS-staged W (r4). FC/pool/softmax unchanged.
// ---------------------------------------------------------------------------

#define BATCH 64
#define NJ 101
#define NI 1152
#define BJ (BATCH * NJ)          // 6464
#define IC 64                    // routing i-chunk per block
#define NIC (NI / IC)            // 18
#define LDW 132                  // routing LDS row stride (words)

static inline int ceil_div(int a, int b) { return (a + b - 1) / b; }

typedef __attribute__((ext_vector_type(8))) short short8;
typedef __attribute__((ext_vector_type(4))) float f32x4;

__device__ __forceinline__ unsigned short f2bf(float f) {
    unsigned u = __float_as_uint(f);
    u += 0x7FFFu + ((u >> 16) & 1u);          // round-to-nearest-even
    return (unsigned short)(u >> 16);
}
__device__ __forceinline__ float bf2f(unsigned short h) {
    return __uint_as_float(((unsigned)h) << 16);
}

// ---------------------------------------------------------------------------
// MFMA implicit-GEMM conv, batch folded into pixel dim.
// C[co,p] = W[co, cin*K*K] x im2col[cin*K*K, p],  p = (b,ho,wo)
// Block: 256 thr = 4 waves. Tile TCO x 64px. Wave = (co half, px half):
// wave-tile (TCO/2)co x 32px = NT x 2 MFMA tiles of 16x16, K-step 32.
// fp32 operands split hi/lo bf16; acc += Ah*Bh + Ah*Bl + Al*Bh (fp32 acc).
// All co/px blocks exact for every conv used here (no epilogue guards).
// ---------------------------------------------------------------------------
template<int K, int STRIDE, int PAD, int WOUT, bool RELU, int TCO>
__global__ __launch_bounds__(256, 3) void conv_mfma(
        const float* __restrict__ in, const float* __restrict__ wgt,
        const float* __restrict__ bias, float* __restrict__ out,
        int CIN, int COUT, int WIN) {
    constexpr int KK  = K * K;
    constexpr int NSP = WOUT * WOUT;
    constexpr int LDH = 40;                 // LDS row stride (halfs), 80 B
    constexpr int NT  = TCO / 32;           // co-tiles per wave
    __shared__ unsigned short Ahs[TCO * LDH], Als[TCO * LDH];
    __shared__ unsigned short Bhs[64 * LDH],  Bls[64 * LDH];

    const int Ktot  = CIN * KK;
    const int WINSQ = WIN * WIN;

    const int tid  = threadIdx.x;
    const int px0  = blockIdx.x * 64;
    const int co0  = blockIdx.y * TCO;
    const int wave = tid >> 6;
    const int lane = tid & 63;
    const int ln15 = lane & 15;
    const int kq   = lane >> 4;             // 0..3
    const int coH  = (wave & 1) * (TCO / 2);
    const int pxH  = (wave >> 1) * 32;

    // ---- hoisted per-thread pixel math (B-gather: px fixed = tid&63) ----
    const int bpx = tid & 63;
    int p    = px0 + bpx;
    int bimg = p / NSP;
    int sp   = p - bimg * NSP;
    int ho   = sp / WOUT;
    int wo   = sp - ho * WOUT;
    const int hi0   = ho * STRIDE - PAD;
    const int wi0   = wo * STRIDE - PAD;
    const int bBase = bimg * CIN * WINSQ;

    f32x4 acc[NT][2];
#pragma unroll
    for (int ct = 0; ct < NT; ++ct)
#pragma unroll
        for (int pt = 0; pt < 2; ++pt)
            acc[ct][pt] = (f32x4){0.f, 0.f, 0.f, 0.f};

    const int nchunks = (Ktot + 31) / 32;
    for (int c = 0; c < nchunks; ++c) {
        const int k0 = c * 32;
        // ---- stage A (weights) TCO x 32, split hi/lo ----
#pragma unroll
        for (int it = 0; it < TCO / 32; ++it) {
            int slot = tid + it * 256;
            int co = slot >> 3;
            int k4 = slot & 7;
            int k  = k0 + k4 * 4;
            float4 w4 = make_float4(0.f, 0.f, 0.f, 0.f);
            const float* wp = wgt + (size_t)(co0 + co) * Ktot + k;
            if (k + 3 < Ktot) {
                w4 = *(const float4*)wp;
            } else {
                if (k + 0 < Ktot) w4.x = wp[0];
                if (k + 1 < Ktot) w4.y = wp[1];
                if (k + 2 < Ktot) w4.z = wp[2];
                if (k + 3 < Ktot) w4.w = wp[3];
            }
            unsigned short h0 = f2bf(w4.x), h1 = f2bf(w4.y),
                           h2 = f2bf(w4.z), h3 = f2bf(w4.w);
            unsigned short l0 = f2bf(w4.x - bf2f(h0)), l1 = f2bf(w4.y - bf2f(h1)),
                           l2 = f2bf(w4.z - bf2f(h2)), l3 = f2bf(w4.w - bf2f(h3));
            *(uint2*)&Ahs[co * LDH + k4 * 4] =
                make_uint2(h0 | ((unsigned)h1 << 16), h2 | ((unsigned)h3 << 16));
            *(uint2*)&Als[co * LDH + k4 * 4] =
                make_uint2(l0 | ((unsigned)l1 << 16), l2 | ((unsigned)l3 << 16));
        }
        // ---- stage B (im2col) 32k x 64px, split hi/lo ----
#pragma unroll
        for (int it = 0; it < 4; ++it) {
            int kp = (tid >> 6) + it * 4;    // k-pair index 0..15
            float f0 = 0.f, f1 = 0.f;
#pragma unroll
            for (int e = 0; e < 2; ++e) {
                int k = k0 + kp * 2 + e;
                float v = 0.f;
                if (k < Ktot) {
                    int ci = k / KK;
                    int r  = k - ci * KK;
                    int kh = r / K;
                    int kw = r - kh * K;
                    int hi = hi0 + kh;
                    int wi = wi0 + kw;
                    bool ok = true;
                    if (PAD > 0)
                        ok = ((unsigned)hi < (unsigned)WIN) &&
                             ((unsigned)wi < (unsigned)WIN);
                    if (ok) v = in[bBase + ci * WINSQ + hi * WIN + wi];
                }
                if (e == 0) f0 = v; else f1 = v;
            }
            unsigned short h0 = f2bf(f0), h1 = f2bf(f1);
            unsigned short l0 = f2bf(f0 - bf2f(h0)), l1 = f2bf(f1 - bf2f(h1));
            *(unsigned*)&Bhs[bpx * LDH + kp * 2] = h0 | ((unsigned)h1 << 16);
            *(unsigned*)&Bls[bpx * LDH + kp * 2] = l0 | ((unsigned)l1 << 16);
        }
        __syncthreads();

        // ---- fragments + MFMA ----
        short8 ahf[NT], alf[NT], bhf[2], blf[2];
#pragma unroll
        for (int ct = 0; ct < NT; ++ct) {
            int m = coH + ct * 16 + ln15;
            ahf[ct] = *(const short8*)&Ahs[m * LDH + kq * 8];
            alf[ct] = *(const short8*)&Als[m * LDH + kq * 8];
        }
#pragma unroll
        for (int pt = 0; pt < 2; ++pt) {
            int n = pxH + pt * 16 + ln15;
            bhf[pt] = *(const short8*)&Bhs[n * LDH + kq * 8];
            blf[pt] = *(const short8*)&Bls[n * LDH + kq * 8];
        }
#pragma unroll
        for (int ct = 0; ct < NT; ++ct)
#pragma unroll
            for (int pt = 0; pt < 2; ++pt) {
                acc[ct][pt] = __builtin_amdgcn_mfma_f32_16x16x32_bf16(
                    ahf[ct], bhf[pt], acc[ct][pt], 0, 0, 0);
                acc[ct][pt] = __builtin_amdgcn_mfma_f32_16x16x32_bf16(
                    ahf[ct], blf[pt], acc[ct][pt], 0, 0, 0);
                acc[ct][pt] = __builtin_amdgcn_mfma_f32_16x16x32_bf16(
                    alf[ct], bhf[pt], acc[ct][pt], 0, 0, 0);
            }
        __syncthreads();
    }

    // ---- epilogue: C/D layout col=lane&15 (px), row=kq*4+reg (co) ----
    float bv[NT][4];
#pragma unroll
    for (int ct = 0; ct < NT; ++ct)
#pragma unroll
        for (int r = 0; r < 4; ++r)
            bv[ct][r] = bias[co0 + coH + ct * 16 + kq * 4 + r];
#pragma unroll
    for (int pt = 0; pt < 2; ++pt) {
        int pg  = px0 + pxH + pt * 16 + ln15;
        int b2  = pg / NSP;
        int sp2 = pg - b2 * NSP;
#pragma unroll
        for (int ct = 0; ct < NT; ++ct) {
#pragma unroll
            for (int r = 0; r < 4; ++r) {
                int co = co0 + coH + ct * 16 + kq * 4 + r;
                float vv = acc[ct][pt][r] + bv[ct][r];
                if (RELU) vv = fmaxf(vv, 0.f);
                out[(size_t)(b2 * COUT + co) * NSP + sp2] = vv;
            }
        }
    }
}

// ---------------------------------------------------------------------------
// FC GEMM: out[m,n] = in[m,:] . w[n,:] + bias[n].  Tile 64n x 64m, chunk 32.
// ---------------------------------------------------------------------------
template<bool RELU>
__global__ __launch_bounds__(256, 4) void fc_gemm(
        const float* __restrict__ in, const float* __restrict__ w,
        const float* __restrict__ bias, float* __restrict__ out,
        int M, int N, int Kd) {
    constexpr int KC  = 32;
    constexpr int LDA = 68;
    __shared__ float Ash[KC * LDA];
    __shared__ float Bsh[KC * LDA];

    const int tid = threadIdx.x;
    const int n0 = blockIdx.x * 64;

    const int tn = tid & 15;
    const int tm = tid >> 4;

    float acc[4][4] = {{0.f}};

    for (int k0 = 0; k0 < Kd; k0 += KC) {
#pragma unroll
        for (int it = 0; it < 2; ++it) {
            int idx = tid + it * 256;
            int n   = idx >> 3;
            int k4  = idx & 7;
            int k   = k0 + k4 * 4;
            float4 w4 = make_float4(0.f, 0.f, 0.f, 0.f);
            int ng = n0 + n;
            if (ng < N) {
                const float* wp = w + (size_t)ng * Kd + k;
                if (k + 3 < Kd) {
                    w4 = *(const float4*)wp;
                } else {
                    if (k + 0 < Kd) w4.x = wp[0];
                    if (k + 1 < Kd) w4.y = wp[1];
                    if (k + 2 < Kd) w4.z = wp[2];
                    if (k + 3 < Kd) w4.w = wp[3];
                }
            }
            Ash[(k4 * 4 + 0) * LDA + n] = w4.x;
            Ash[(k4 * 4 + 1) * LDA + n] = w4.y;
            Ash[(k4 * 4 + 2) * LDA + n] = w4.z;
            Ash[(k4 * 4 + 3) * LDA + n] = w4.w;
        }
#pragma unroll
        for (int it = 0; it < 2; ++it) {
            int idx = tid + it * 256;
            int m   = idx >> 3;
            int k4  = idx & 7;
            int k   = k0 + k4 * 4;
            float4 x4 = make_float4(0.f, 0.f, 0.f, 0.f);
            if (m < M) {
                const float* xp = in + (size_t)m * Kd + k;
                if (k + 3 < Kd) {
                    x4 = *(const float4*)xp;
                } else {
                    if (k + 0 < Kd) x4.x = xp[0];
                    if (k + 1 < Kd) x4.y = xp[1];
                    if (k + 2 < Kd) x4.z = xp[2];
                    if (k + 3 < Kd) x4.w = xp[3];
                }
            }
            Bsh[(k4 * 4 + 0) * LDA + m] = x4.x;
            Bsh[(k4 * 4 + 1) * LDA + m] = x4.y;
            Bsh[(k4 * 4 + 2) * LDA + m] = x4.z;
            Bsh[(k4 * 4 + 3) * LDA + m] = x4.w;
        }
        __syncthreads();
#pragma unroll
        for (int kk = 0; kk < KC; ++kk) {
            float4 a4 = *(const float4*)&Ash[kk * LDA + tn * 4];
            float4 b4 = *(const float4*)&Bsh[kk * LDA + tm * 4];
            float av[4] = {a4.x, a4.y, a4.z, a4.w};
            float bv[4] = {b4.x, b4.y, b4.z, b4.w};
#pragma unroll
            for (int i = 0; i < 4; ++i)
#pragma unroll
                for (int j = 0; j < 4; ++j)
                    acc[i][j] = fmaf(av[i], bv[j], acc[i][j]);
        }
        __syncthreads();
    }

#pragma unroll
    for (int i = 0; i < 4; ++i) {
        int ng = n0 + tn * 4 + i;
        if (ng >= N) continue;
        float bs = bias[ng];
#pragma unroll
        for (int j = 0; j < 4; ++j) {
            int m = tm * 4 + j;
            if (m >= M) continue;
            float vv = acc[i][j] + bs;
            if (RELU) vv = fmaxf(vv, 0.f);
            out[(size_t)m * N + ng] = vv;
        }
    }
}

// ---------------- maxpool ---------------------------------------------------
__global__ void maxpool_k(const float* __restrict__ in, float* __restrict__ out,
                          int BC, int HIN, int WIN, int HOUT, int WOUT,
                          int KS, int S, int P) {
    int idx = blockIdx.x * blockDim.x + threadIdx.x;
    int total = BC * HOUT * WOUT;
    if (idx >= total) return;
    int wo = idx % WOUT;
    int ho = (idx / WOUT) % HOUT;
    int bc = idx / (WOUT * HOUT);
    int h0 = ho * S - P, w0 = wo * S - P;
    int h1 = h0 + KS, w1 = w0 + KS;
    if (h0 < 0) h0 = 0;
    if (w0 < 0) w0 = 0;
    if (h1 > HIN) h1 = HIN;
    if (w1 > WIN) w1 = WIN;
    const float* base = in + (size_t)bc * HIN * WIN;
    float m = -INFINITY;
    for (int h = h0; h < h1; h++)
        for (int w = w0; w < w1; w++)
            m = fmaxf(m, base[h * WIN + w]);
    out[idx] = m;
}

// ---------------- squash over trailing dim of 8 ----------------------------
__global__ void squash_u(const float* __restrict__ p, float* __restrict__ u, int ncaps) {
    int idx = blockIdx.x * blockDim.x + threadIdx.x;
    if (idx >= ncaps) return;
    const float4* pp = (const float4*)(p + (size_t)idx * 8);
    float4 a = pp[0], b = pp[1];
    float sq = a.x*a.x + a.y*a.y + a.z*a.z + a.w*a.w
             + b.x*b.x + b.y*b.y + b.z*b.z + b.w*b.w;
    float scale = (sq / (1.f + sq)) / sqrtf(sq + 1e-8f);
    float4* uu = (float4*)(u + (size_t)idx * 8);
    float4 oa, ob;
    oa.x = a.x*scale; oa.y = a.y*scale; oa.z = a.z*scale; oa.w = a.w*scale;
    ob.x = b.x*scale; ob.y = b.y*scale; ob.z = b.z*scale; ob.w = b.w*scale;
    uu[0] = oa; uu[1] = ob;
}

// ---------------- softmax over J (axis=1 of [B,J,I]) -----------------------
__global__ void softmax_j(const float* __restrict__ blog, float* __restrict__ c,
                          int Bn, int J, int I) {
    int idx = blockIdx.x * blockDim.x + threadIdx.x;
    if (idx >= Bn * I) return;
    int b = idx / I, i = idx - b * I;
    const float* base = blog + (size_t)b * J * I + i;
    float m = -INFINITY;
    for (int j = 0; j < J; j++) m = fmaxf(m, base[(size_t)j * I]);
    float* cb = c + (size_t)b * J * I + i;
    float sum = 0.f;
    for (int j = 0; j < J; j++) {
        float e = expf(base[(size_t)j * I] - m);
        sum += e;
        cb[(size_t)j * I] = e;
    }
    float inv = 1.f / sum;
    for (int j = 0; j < J; j++) cb[(size_t)j * I] *= inv;
}

// ===========================================================================
// Routing, LDS-staged-W (round 4, proven).
// ===========================================================================
__device__ __forceinline__ void stage_W(const float* __restrict__ W,
                                        float* __restrict__ wsh,
                                        int j, int i0, int tid) {
    const float4* Wp = (const float4*)(W + ((size_t)j * NI + i0) * 128);
#pragma unroll
    for (int p = 0; p < 8; ++p) {
        int vi  = p * 256 + tid;
        int row = vi >> 5;
        int c4  = vi & 31;
        float4 f = Wp[vi];
        *(float4*)&wsh[row * LDW + c4 * 4] = f;
    }
}

__global__ __launch_bounds__(256) void route_s_w(
        const float* __restrict__ c, const float* __restrict__ u,
        const float* __restrict__ W, float* __restrict__ ppart, int uniform) {
    __shared__ float wsh[IC * LDW];
    const int tid = threadIdx.x;
    const int icb = blockIdx.x;
    const int j   = blockIdx.y;
    const int i0  = icb * IC;

    stage_W(W, wsh, j, i0, tid);
    __syncthreads();

    const int bg = tid >> 4;
    const int iq = tid & 15;
    const float invJ = 1.f / (float)NJ;

    float s[4][16];
#pragma unroll
    for (int bb = 0; bb < 4; ++bb)
#pragma unroll
        for (int o = 0; o < 16; ++o) s[bb][o] = 0.f;

#pragma unroll
    for (int k = 0; k < 4; ++k) {
        int il = iq + 16 * k;
        int ig = i0 + il;
        const float* wr = &wsh[il * LDW];
        float4 ua[4], ub[4];
        float cc[4];
#pragma unroll
        for (int bb = 0; bb < 4; ++bb) {
            int b = bg * 4 + bb;
            const float4* up = (const float4*)(u + ((size_t)b * NI + ig) * 8);
            ua[bb] = up[0];
            ub[bb] = up[1];
            cc[bb] = uniform ? invJ : c[((size_t)b * NJ + j) * NI + ig];
        }
#pragma unroll
        for (int o = 0; o < 16; ++o) {
            float4 w0 = *(const float4*)&wr[o * 8];
            float4 w1 = *(const float4*)&wr[o * 8 + 4];
#pragma unroll
            for (int bb = 0; bb < 4; ++bb) {
                float dot = w0.x*ua[bb].x + w0.y*ua[bb].y + w0.z*ua[bb].z + w0.w*ua[bb].w
                          + w1.x*ub[bb].x + w1.y*ub[bb].y + w1.z*ub[bb].z + w1.w*ub[bb].w;
                s[bb][o] = fmaf(cc[bb], dot, s[bb][o]);
            }
        }
    }

#pragma unroll
    for (int off = 8; off > 0; off >>= 1)
#pragma unroll
        for (int bb = 0; bb < 4; ++bb)
#pragma unroll
            for (int o = 0; o < 16; ++o)
                s[bb][o] += __shfl_down(s[bb][o], off, 16);

    if (iq == 0) {
#pragma unroll
        for (int bb = 0; bb < 4; ++bb) {
            int b = bg * 4 + bb;
            size_t base = ((size_t)icb * BJ + (size_t)b * NJ + j) * 16;
#pragma unroll
            for (int o4 = 0; o4 < 4; ++o4)
                *(float4*)&ppart[base + o4 * 4] =
                    make_float4(s[bb][o4*4+0], s[bb][o4*4+1], s[bb][o4*4+2], s[bb][o4*4+3]);
        }
    }
}

__global__ __launch_bounds__(64) void reduce_squash(
        const float* __restrict__ ppart, float* __restrict__ v) {
    int l = threadIdx.x >> 4;
    int o = threadIdx.x & 15;
    int bj = blockIdx.x * 4 + l;
    float s = 0.f;
    for (int ic = 0; ic < NIC; ic++)
        s += ppart[((size_t)ic * BJ + bj) * 16 + o];
    __shared__ float sarr[4][16];
    sarr[l][o] = s;
    __syncthreads();
    float ssq = 0.f;
#pragma unroll
    for (int k = 0; k < 16; k++) { float t = sarr[l][k]; ssq += t * t; }
    float scale = (ssq / (1.f + ssq)) / sqrtf(ssq + 1e-8f);
    v[(size_t)bj * 16 + o] = s * scale;
}

__global__ __launch_bounds__(256) void route_bupd_w(
        const float* __restrict__ u, const float* __restrict__ W,
        const float* __restrict__ v, float* __restrict__ blog, int accumulate) {
    __shared__ float wsh[IC * LDW];
    const int tid = threadIdx.x;
    const int icb = blockIdx.x;
    const int j   = blockIdx.y;
    const int i0  = icb * IC;

    stage_W(W, wsh, j, i0, tid);
    __syncthreads();

    const int bg = tid >> 4;
    const int iq = tid & 15;

    float vv[4][16];
#pragma unroll
    for (int bb = 0; bb < 4; ++bb) {
        int b = bg * 4 + bb;
        const float4* vp = (const float4*)(v + ((size_t)b * NJ + j) * 16);
#pragma unroll
        for (int o4 = 0; o4 < 4; ++o4) {
            float4 f = vp[o4];
            vv[bb][o4*4+0] = f.x; vv[bb][o4*4+1] = f.y;
            vv[bb][o4*4+2] = f.z; vv[bb][o4*4+3] = f.w;
        }
    }

#pragma unroll
    for (int k = 0; k < 4; ++k) {
        int il = iq + 16 * k;
        int ig = i0 + il;
        const float* wr = &wsh[il * LDW];
        float4 ua[4], ub[4];
#pragma unroll
        for (int bb = 0; bb < 4; ++bb) {
            int b = bg * 4 + bb;
            const float4* up = (const float4*)(u + ((size_t)b * NI + ig) * 8);
            ua[bb] = up[0];
            ub[bb] = up[1];
        }
        float acc[4] = {0.f, 0.f, 0.f, 0.f};
#pragma unroll
        for (int o = 0; o < 16; ++o) {
            float4 w0 = *(const float4*)&wr[o * 8];
            float4 w1 = *(const float4*)&wr[o * 8 + 4];
#pragma unroll
            for (int bb = 0; bb < 4; ++bb) {
                float dot = w0.x*ua[bb].x + w0.y*ua[bb].y + w0.z*ua[bb].z + w0.w*ua[bb].w
                          + w1.x*ub[bb].x + w1.y*ub[bb].y + w1.z*ub[bb].z + w1.w*ub[bb].w;
                acc[bb] = fmaf(vv[bb][o], dot, acc[bb]);
            }
        }
#pragma unroll
        for (int bb = 0; bb < 4; ++bb) {
            int b = bg * 4 + bb;
            size_t idx = ((size_t)b * NJ + j) * NI + ig;
            blog[idx] = accumulate ? (blog[idx] + acc[bb]) : acc[bb];
        }
    }
}

// ---------------------------------------------------------------------------
extern "C" void kernel_launch(void* const* d_in, const int* in_sizes, int n_in,
                              void* d_out, int out_size, void* d_ws, size_t ws_size,
                              hipStream_t stream) {
    const float* x     = (const float*)d_in[0];
    const float* w1    = (const float*)d_in[1];
    const float* b1    = (const float*)d_in[2];
    const float* w2    = (const float*)d_in[3];
    const float* b2    = (const float*)d_in[4];
    const float* w3    = (const float*)d_in[5];
    const float* b3    = (const float*)d_in[6];
    const float* w4    = (const float*)d_in[7];
    const float* b4    = (const float*)d_in[8];
    const float* w5    = (const float*)d_in[9];
    const float* b5    = (const float*)d_in[10];
    const float* pc_w  = (const float*)d_in[11];
    const float* pc_b  = (const float*)d_in[12];
    const float* capsW = (const float*)d_in[13];
    const float* fc1_w = (const float*)d_in[14];
    const float* fc1_b = (const float*)d_in[15];
    const float* fc2_w = (const float*)d_in[16];
    const float* fc2_b = (const float*)d_in[17];
    const float* fc3_w = (const float*)d_in[18];
    const float* fc3_b = (const float*)d_in[19];
    float* outp = (float*)d_out;

    // ws layout: A (80 MB) | Bb (20 MB) | Dd (4 MB)
    char* ws = (char*)d_ws;
    float* A  = (float*)ws;
    float* Bb = (float*)(ws + ((size_t)80 << 20));
    float* Dd = (float*)(ws + ((size_t)100 << 20));
    float* blog  = A;                        // [64,101,1152]
    float* csm   = A + 7446528;              // [64,101,1152]
    float* ppart = A + 2 * 7446528;          // [18][6464][16]
    float* vcap = Dd;                        // [64,101,16]
    float* f1   = Dd + 131072;
    float* f2   = Dd + 131072 + 262144;

    const int B = BATCH;

    // ---- conv stack (bf16x3 MFMA implicit GEMM, batch-folded) ----
    // conv1: [64,3,227,227] -> [64,96,55,55]; px_tot = 193600 = 3025*64
    conv_mfma<11, 4, 0, 55, true, 96><<<dim3(3025, 1), dim3(256), 0, stream>>>(
        x, w1, b1, A, 3, 96, 227);
    maxpool_k<<<dim3(ceil_div(B * 96 * 27 * 27, 256)), dim3(256), 0, stream>>>(
        A, Bb, B * 96, 55, 55, 27, 27, 3, 2, 0);
    // conv2: [64,96,27,27] -> [64,256,27,27]; px_tot = 46656 = 729*64
    conv_mfma<5, 1, 2, 27, true, 128><<<dim3(729, 2), dim3(256), 0, stream>>>(
        Bb, w2, b2, A, 96, 256, 27);
    maxpool_k<<<dim3(ceil_div(B * 256 * 14 * 14, 256)), dim3(256), 0, stream>>>(
        A, Bb, B * 256, 27, 27, 14, 14, 3, 2, 1);
    // conv3: [64,256,14,14] -> [64,384,14,14]; px_tot = 12544 = 196*64
    conv_mfma<3, 1, 1, 14, true, 128><<<dim3(196, 3), dim3(256), 0, stream>>>(
        Bb, w3, b3, A, 256, 384, 14);
    // conv4
    conv_mfma<3, 1, 1, 14, true, 128><<<dim3(196, 3), dim3(256), 0, stream>>>(
        A, w4, b4, Bb, 384, 384, 14);
    // conv5
    conv_mfma<3, 1, 1, 14, true, 128><<<dim3(196, 2), dim3(256), 0, stream>>>(
        Bb, w5, b5, A, 384, 256, 14);
    maxpool_k<<<dim3(ceil_div(B * 256 * 6 * 6, 256)), dim3(256), 0, stream>>>(
        A, Bb, B * 256, 14, 14, 6, 6, 3, 2, 0);
    // primarycaps conv: [64,256,6,6] -> [64,256,6,6]; px_tot = 2304 = 36*64
    conv_mfma<3, 1, 1, 6, false, 64><<<dim3(36, 4), dim3(256), 0, stream>>>(
        Bb, pc_w, pc_b, A, 256, 256, 6);
    squash_u<<<dim3(ceil_div(B * 1152, 256)), dim3(256), 0, stream>>>(A, Bb, B * 1152);
    // u now in Bb [64,1152,8]

    // ---- dynamic routing (3 iters), W staged in LDS ----
    dim3 rgrid(NIC, NJ);
    route_s_w<<<rgrid, dim3(256), 0, stream>>>(csm, Bb, capsW, ppart, 1);
    reduce_squash<<<dim3(BJ / 4), dim3(64), 0, stream>>>(ppart, vcap);
    route_bupd_w<<<rgrid, dim3(256), 0, stream>>>(Bb, capsW, vcap, blog, 0);
    softmax_j<<<dim3(ceil_div(B * NI, 256)), dim3(256), 0, stream>>>(
        blog, csm, B, NJ, NI);
    route_s_w<<<rgrid, dim3(256), 0, stream>>>(csm, Bb, capsW, ppart, 0);
    reduce_squash<<<dim3(BJ / 4), dim3(64), 0, stream>>>(ppart, vcap);
    route_bupd_w<<<rgrid, dim3(256), 0, stream>>>(Bb, capsW, vcap, blog, 1);
    softmax_j<<<dim3(ceil_div(B * NI, 256)), dim3(256), 0, stream>>>(
        blog, csm, B, NJ, NI);
    route_s_w<<<rgrid, dim3(256), 0, stream>>>(csm, Bb, capsW, ppart, 0);
    reduce_squash<<<dim3(BJ / 4), dim3(64), 0, stream>>>(ppart, vcap);

    // ---- MLP head ----
    fc_gemm<true><<<dim3(64), dim3(256), 0, stream>>>(vcap, fc1_w, fc1_b, f1, B, 4096, 1616);
    fc_gemm<true><<<dim3(64), dim3(256), 0, stream>>>(f1, fc2_w, fc2_b, f2, B, 4096, 4096);
    fc_gemm<false><<<dim3(2), dim3(256), 0, stream>>>(f2, fc3_w, fc3_b, outp, B, 101, 4096);
}

// Round 8
// 3484.748 us; speedup vs baseline: 2.0539x; 1.1243x over previous
//
#include <hip/hip_runtime.h>
#include <math.h>

// ---------------------------------------------------------------------------
// AlexCapsNet (FOOD101) forward. Round 8: bf16x3 MFMA convs with HOISTED
// splitting — weights pre-split to hi/lo planes (ws-gated), activations
// carried packed (hi<<16|lo). Routing: LDS-staged W. FC fp32 GEMM.
// ---------------------------------------------------------------------------

#define BATCH 64
#define NJ 101
#define NI 1152
#define BJ (BATCH * NJ)
#define IC 64
#define NIC (NI / IC)
#define LDW 132

static inline int ceil_div(int a, int b) { return (a + b - 1) / b; }

typedef __attribute__((ext_vector_type(8))) short short8;
typedef __attribute__((ext_vector_type(4))) float f32x4;

__device__ __forceinline__ unsigned short f2bf(float f) {
    unsigned u = __float_as_uint(f);
    u += 0x7FFFu + ((u >> 16) & 1u);
    return (unsigned short)(u >> 16);
}
__device__ __forceinline__ float bf2f(unsigned short h) {
    return __uint_as_float(((unsigned)h) << 16);
}
__device__ __forceinline__ unsigned packsplit(float v) {
    unsigned short h = f2bf(v);
    unsigned short l = f2bf(v - bf2f(h));
    return ((unsigned)h << 16) | l;
}

// ---------------- weight pre-split: fp32 [co][Ktot] -> hi/lo [co][Kp] ------
__global__ void split_w(const float* __restrict__ w, unsigned short* __restrict__ hi,
                        unsigned short* __restrict__ lo, int Ktot, int Kp, int total) {
    int idx = blockIdx.x * 256 + threadIdx.x;
    if (idx >= total) return;
    int co = idx / Kp, kp = idx - co * Kp;
    float v = (kp < Ktot) ? w[(size_t)co * Ktot + kp] : 0.f;
    unsigned short h = f2bf(v);
    hi[idx] = h;
    lo[idx] = f2bf(v - bf2f(h));
}

// ---------------------------------------------------------------------------
// MFMA implicit-GEMM conv (bf16x3 split), batch folded into pixel dim.
// INPK: input is packed (hi<<16|lo) uint; else fp32 (split inline).
// OUTPK: output packed uint; else fp32.
// whi/wlo: pre-split weight planes (row stride Kp); null -> inline split.
// ---------------------------------------------------------------------------
template<int K, int STRIDE, int PAD, int WOUT, bool RELU, int TCO,
         bool INPK, bool OUTPK>
__global__ __launch_bounds__(256, 4) void conv_mfma(
        const void* __restrict__ inv, const float* __restrict__ wgt,
        const unsigned short* __restrict__ whi, const unsigned short* __restrict__ wlo,
        const float* __restrict__ bias, void* __restrict__ outv,
        int CIN, int COUT, int WIN, int Kp) {
    constexpr int KK  = K * K;
    constexpr int NSP = WOUT * WOUT;
    constexpr int LDH = 40;
    constexpr int NT  = TCO / 32;
    __shared__ unsigned short Ahs[TCO * LDH], Als[TCO * LDH];
    __shared__ unsigned short Bhs[64 * LDH],  Bls[64 * LDH];

    const int Ktot  = CIN * KK;
    const int WINSQ = WIN * WIN;

    const int tid  = threadIdx.x;
    const int px0  = blockIdx.x * 64;
    const int co0  = blockIdx.y * TCO;
    const int wave = tid >> 6;
    const int lane = tid & 63;
    const int ln15 = lane & 15;
    const int kq   = lane >> 4;
    const int coH  = (wave & 1) * (TCO / 2);
    const int pxH  = (wave >> 1) * 32;

    // hoisted per-thread pixel math (B-gather: px fixed = tid&63)
    const int bpx = tid & 63;
    int p    = px0 + bpx;
    int bimg = p / NSP;
    int sp   = p - bimg * NSP;
    int ho   = sp / WOUT;
    int wo   = sp - ho * WOUT;
    const int hi0   = ho * STRIDE - PAD;
    const int wi0   = wo * STRIDE - PAD;
    const int bBase = bimg * CIN * WINSQ;

    const int aco = tid >> 3;       // A staging role
    const int ak4 = tid & 7;

    f32x4 acc[NT][2];
#pragma unroll
    for (int ct = 0; ct < NT; ++ct)
#pragma unroll
        for (int pt = 0; pt < 2; ++pt)
            acc[ct][pt] = (f32x4){0.f, 0.f, 0.f, 0.f};

    const int nchunks = (Ktot + 31) / 32;
    for (int c = 0; c < nchunks; ++c) {
        const int k0 = c * 32;
        // ---- stage A (weights) TCO x 32 ----
        if (whi) {
#pragma unroll
            for (int it = 0; it < TCO / 32; ++it) {
                int slot = tid + it * 256;
                int co = slot >> 3;
                int k4 = slot & 7;
                int row = (co0 + co) * Kp + k0 + k4 * 4;
                ushort4 h4 = *(const ushort4*)&whi[row];
                ushort4 l4 = *(const ushort4*)&wlo[row];
                *(ushort4*)&Ahs[co * LDH + k4 * 4] = h4;
                *(ushort4*)&Als[co * LDH + k4 * 4] = l4;
            }
        } else {
#pragma unroll
            for (int it = 0; it < TCO / 32; ++it) {
                int slot = tid + it * 256;
                int co = slot >> 3;
                int k4 = slot & 7;
                int k  = k0 + k4 * 4;
                float4 w4 = make_float4(0.f, 0.f, 0.f, 0.f);
                const float* wp = wgt + (size_t)(co0 + co) * Ktot + k;
                if (k + 3 < Ktot) {
                    w4 = *(const float4*)wp;
                } else {
                    if (k + 0 < Ktot) w4.x = wp[0];
                    if (k + 1 < Ktot) w4.y = wp[1];
                    if (k + 2 < Ktot) w4.z = wp[2];
                    if (k + 3 < Ktot) w4.w = wp[3];
                }
                unsigned short h0 = f2bf(w4.x), h1 = f2bf(w4.y),
                               h2 = f2bf(w4.z), h3 = f2bf(w4.w);
                unsigned short l0 = f2bf(w4.x - bf2f(h0)), l1 = f2bf(w4.y - bf2f(h1)),
                               l2 = f2bf(w4.z - bf2f(h2)), l3 = f2bf(w4.w - bf2f(h3));
                *(uint2*)&Ahs[co * LDH + k4 * 4] =
                    make_uint2(h0 | ((unsigned)h1 << 16), h2 | ((unsigned)h3 << 16));
                *(uint2*)&Als[co * LDH + k4 * 4] =
                    make_uint2(l0 | ((unsigned)l1 << 16), l2 | ((unsigned)l3 << 16));
            }
        }
        // ---- stage B (im2col) 32k x 64px ----
#pragma unroll
        for (int it = 0; it < 4; ++it) {
            int kp = (tid >> 6) + it * 4;     // k-pair index 0..15
            if (INPK) {
                const unsigned* inp = (const unsigned*)inv;
                unsigned u0 = 0, u1 = 0;
#pragma unroll
                for (int e = 0; e < 2; ++e) {
                    int k = k0 + kp * 2 + e;
                    unsigned v = 0;
                    if (k < Ktot) {
                        int ci = k / KK;
                        int r  = k - ci * KK;
                        int kh = r / K;
                        int kw = r - kh * K;
                        int hh = hi0 + kh;
                        int ww = wi0 + kw;
                        bool ok = true;
                        if (PAD > 0)
                            ok = ((unsigned)hh < (unsigned)WIN) &&
                                 ((unsigned)ww < (unsigned)WIN);
                        if (ok) v = inp[bBase + ci * WINSQ + hh * WIN + ww];
                    }
                    if (e == 0) u0 = v; else u1 = v;
                }
                *(unsigned*)&Bhs[bpx * LDH + kp * 2] = (u0 >> 16) | (u1 & 0xFFFF0000u);
                *(unsigned*)&Bls[bpx * LDH + kp * 2] = (u0 & 0xFFFFu) | (u1 << 16);
            } else {
                const float* inp = (const float*)inv;
                float f0 = 0.f, f1 = 0.f;
#pragma unroll
                for (int e = 0; e < 2; ++e) {
                    int k = k0 + kp * 2 + e;
                    float v = 0.f;
                    if (k < Ktot) {
                        int ci = k / KK;
                        int r  = k - ci * KK;
                        int kh = r / K;
                        int kw = r - kh * K;
                        int hh = hi0 + kh;
                        int ww = wi0 + kw;
                        bool ok = true;
                        if (PAD > 0)
                            ok = ((unsigned)hh < (unsigned)WIN) &&
                                 ((unsigned)ww < (unsigned)WIN);
                        if (ok) v = inp[bBase + ci * WINSQ + hh * WIN + ww];
                    }
                    if (e == 0) f0 = v; else f1 = v;
                }
                unsigned short h0 = f2bf(f0), h1 = f2bf(f1);
                unsigned short l0 = f2bf(f0 - bf2f(h0)), l1 = f2bf(f1 - bf2f(h1));
                *(unsigned*)&Bhs[bpx * LDH + kp * 2] = h0 | ((unsigned)h1 << 16);
                *(unsigned*)&Bls[bpx * LDH + kp * 2] = l0 | ((unsigned)l1 << 16);
            }
        }
        __syncthreads();

        // ---- fragments + MFMA (3-term split product) ----
        short8 ahf[NT], alf[NT], bhf[2], blf[2];
#pragma unroll
        for (int ct = 0; ct < NT; ++ct) {
            int m = coH + ct * 16 + ln15;
            ahf[ct] = *(const short8*)&Ahs[m * LDH + kq * 8];
            alf[ct] = *(const short8*)&Als[m * LDH + kq * 8];
        }
#pragma unroll
        for (int pt = 0; pt < 2; ++pt) {
            int n = pxH + pt * 16 + ln15;
            bhf[pt] = *(const short8*)&Bhs[n * LDH + kq * 8];
            blf[pt] = *(const short8*)&Bls[n * LDH + kq * 8];
        }
#pragma unroll
        for (int ct = 0; ct < NT; ++ct)
#pragma unroll
            for (int pt = 0; pt < 2; ++pt) {
                acc[ct][pt] = __builtin_amdgcn_mfma_f32_16x16x32_bf16(
                    ahf[ct], bhf[pt], acc[ct][pt], 0, 0, 0);
                acc[ct][pt] = __builtin_amdgcn_mfma_f32_16x16x32_bf16(
                    ahf[ct], blf[pt], acc[ct][pt], 0, 0, 0);
                acc[ct][pt] = __builtin_amdgcn_mfma_f32_16x16x32_bf16(
                    alf[ct], bhf[pt], acc[ct][pt], 0, 0, 0);
            }
        __syncthreads();
    }

    // ---- epilogue: C/D layout col=lane&15 (px), row=kq*4+reg (co) ----
    float bv[NT][4];
#pragma unroll
    for (int ct = 0; ct < NT; ++ct)
#pragma unroll
        for (int r = 0; r < 4; ++r)
            bv[ct][r] = bias[co0 + coH + ct * 16 + kq * 4 + r];
#pragma unroll
    for (int pt = 0; pt < 2; ++pt) {
        int pg  = px0 + pxH + pt * 16 + ln15;
        int b2  = pg / NSP;
        int sp2 = pg - b2 * NSP;
#pragma unroll
        for (int ct = 0; ct < NT; ++ct) {
#pragma unroll
            for (int r = 0; r < 4; ++r) {
                int co = co0 + coH + ct * 16 + kq * 4 + r;
                float vv = acc[ct][pt][r] + bv[ct][r];
                if (RELU) vv = fmaxf(vv, 0.f);
                size_t oi = (size_t)(b2 * COUT + co) * NSP + sp2;
                if (OUTPK) ((unsigned*)outv)[oi] = packsplit(vv);
                else       ((float*)outv)[oi] = vv;
            }
        }
    }
}

// ---------------- maxpool fp32 -> packed -----------------------------------
__global__ void maxpool_pack(const float* __restrict__ in, unsigned* __restrict__ out,
                             int BC, int HIN, int WIN, int HOUT, int WOUT,
                             int KS, int S, int P) {
    int idx = blockIdx.x * blockDim.x + threadIdx.x;
    int total = BC * HOUT * WOUT;
    if (idx >= total) return;
    int wo = idx % WOUT;
    int ho = (idx / WOUT) % HOUT;
    int bc = idx / (WOUT * HOUT);
    int h0 = ho * S - P, w0 = wo * S - P;
    int h1 = h0 + KS, w1 = w0 + KS;
    if (h0 < 0) h0 = 0;
    if (w0 < 0) w0 = 0;
    if (h1 > HIN) h1 = HIN;
    if (w1 > WIN) w1 = WIN;
    const float* base = in + (size_t)bc * HIN * WIN;
    float m = -INFINITY;
    for (int h = h0; h < h1; h++)
        for (int w = w0; w < w1; w++)
            m = fmaxf(m, base[h * WIN + w]);
    out[idx] = packsplit(m);
}

// ---------------- squash over trailing dim of 8 ----------------------------
__global__ void squash_u(const float* __restrict__ p, float* __restrict__ u, int ncaps) {
    int idx = blockIdx.x * blockDim.x + threadIdx.x;
    if (idx >= ncaps) return;
    const float4* pp = (const float4*)(p + (size_t)idx * 8);
    float4 a = pp[0], b = pp[1];
    float sq = a.x*a.x + a.y*a.y + a.z*a.z + a.w*a.w
             + b.x*b.x + b.y*b.y + b.z*b.z + b.w*b.w;
    float scale = (sq / (1.f + sq)) / sqrtf(sq + 1e-8f);
    float4* uu = (float4*)(u + (size_t)idx * 8);
    float4 oa, ob;
    oa.x = a.x*scale; oa.y = a.y*scale; oa.z = a.z*scale; oa.w = a.w*scale;
    ob.x = b.x*scale; ob.y = b.y*scale; ob.z = b.z*scale; ob.w = b.w*scale;
    uu[0] = oa; uu[1] = ob;
}

// ---------------- softmax over J -------------------------------------------
__global__ void softmax_j(const float* __restrict__ blog, float* __restrict__ c,
                          int Bn, int J, int I) {
    int idx = blockIdx.x * blockDim.x + threadIdx.x;
    if (idx >= Bn * I) return;
    int b = idx / I, i = idx - b * I;
    const float* base = blog + (size_t)b * J * I + i;
    float m = -INFINITY;
    for (int j = 0; j < J; j++) m = fmaxf(m, base[(size_t)j * I]);
    float* cb = c + (size_t)b * J * I + i;
    float sum = 0.f;
    for (int j = 0; j < J; j++) {
        float e = expf(base[(size_t)j * I] - m);
        sum += e;
        cb[(size_t)j * I] = e;
    }
    float inv = 1.f / sum;
    for (int j = 0; j < J; j++) cb[(size_t)j * I] *= inv;
}

// ===========================================================================
// Routing, LDS-staged-W (round 4, proven).
// ===========================================================================
__device__ __forceinline__ void stage_W(const float* __restrict__ W,
                                        float* __restrict__ wsh,
                                        int j, int i0, int tid) {
    const float4* Wp = (const float4*)(W + ((size_t)j * NI + i0) * 128);
#pragma unroll
    for (int p = 0; p < 8; ++p) {
        int vi  = p * 256 + tid;
        int row = vi >> 5;
        int c4  = vi & 31;
        float4 f = Wp[vi];
        *(float4*)&wsh[row * LDW + c4 * 4] = f;
    }
}

__global__ __launch_bounds__(256) void route_s_w(
        const float* __restrict__ c, const float* __restrict__ u,
        const float* __restrict__ W, float* __restrict__ ppart, int uniform) {
    __shared__ float wsh[IC * LDW];
    const int tid = threadIdx.x;
    const int icb = blockIdx.x;
    const int j   = blockIdx.y;
    const int i0  = icb * IC;

    stage_W(W, wsh, j, i0, tid);
    __syncthreads();

    const int bg = tid >> 4;
    const int iq = tid & 15;
    const float invJ = 1.f / (float)NJ;

    float s[4][16];
#pragma unroll
    for (int bb = 0; bb < 4; ++bb)
#pragma unroll
        for (int o = 0; o < 16; ++o) s[bb][o] = 0.f;

#pragma unroll
    for (int k = 0; k < 4; ++k) {
        int il = iq + 16 * k;
        int ig = i0 + il;
        const float* wr = &wsh[il * LDW];
        float4 ua[4], ub[4];
        float cc[4];
#pragma unroll
        for (int bb = 0; bb < 4; ++bb) {
            int b = bg * 4 + bb;
            const float4* up = (const float4*)(u + ((size_t)b * NI + ig) * 8);
            ua[bb] = up[0];
            ub[bb] = up[1];
            cc[bb] = uniform ? invJ : c[((size_t)b * NJ + j) * NI + ig];
        }
#pragma unroll
        for (int o = 0; o < 16; ++o) {
            float4 w0 = *(const float4*)&wr[o * 8];
            float4 w1 = *(const float4*)&wr[o * 8 + 4];
#pragma unroll
            for (int bb = 0; bb < 4; ++bb) {
                float dot = w0.x*ua[bb].x + w0.y*ua[bb].y + w0.z*ua[bb].z + w0.w*ua[bb].w
                          + w1.x*ub[bb].x + w1.y*ub[bb].y + w1.z*ub[bb].z + w1.w*ub[bb].w;
                s[bb][o] = fmaf(cc[bb], dot, s[bb][o]);
            }
        }
    }

#pragma unroll
    for (int off = 8; off > 0; off >>= 1)
#pragma unroll
        for (int bb = 0; bb < 4; ++bb)
#pragma unroll
            for (int o = 0; o < 16; ++o)
                s[bb][o] += __shfl_down(s[bb][o], off, 16);

    if (iq == 0) {
#pragma unroll
        for (int bb = 0; bb < 4; ++bb) {
            int b = bg * 4 + bb;
            size_t base = ((size_t)icb * BJ + (size_t)b * NJ + j) * 16;
#pragma unroll
            for (int o4 = 0; o4 < 4; ++o4)
                *(float4*)&ppart[base + o4 * 4] =
                    make_float4(s[bb][o4*4+0], s[bb][o4*4+1], s[bb][o4*4+2], s[bb][o4*4+3]);
        }
    }
}

__global__ __launch_bounds__(64) void reduce_squash(
        const float* __restrict__ ppart, float* __restrict__ v) {
    int l = threadIdx.x >> 4;
    int o = threadIdx.x & 15;
    int bj = blockIdx.x * 4 + l;
    float s = 0.f;
    for (int ic = 0; ic < NIC; ic++)
        s += ppart[((size_t)ic * BJ + bj) * 16 + o];
    __shared__ float sarr[4][16];
    sarr[l][o] = s;
    __syncthreads();
    float ssq = 0.f;
#pragma unroll
    for (int k = 0; k < 16; k++) { float t = sarr[l][k]; ssq += t * t; }
    float scale = (ssq / (1.f + ssq)) / sqrtf(ssq + 1e-8f);
    v[(size_t)bj * 16 + o] = s * scale;
}

__global__ __launch_bounds__(256) void route_bupd_w(
        const float* __restrict__ u, const float* __restrict__ W,
        const float* __restrict__ v, float* __restrict__ blog, int accumulate) {
    __shared__ float wsh[IC * LDW];
    const int tid = threadIdx.x;
    const int icb = blockIdx.x;
    const int j   = blockIdx.y;
    const int i0  = icb * IC;

    stage_W(W, wsh, j, i0, tid);
    __syncthreads();

    const int bg = tid >> 4;
    const int iq = tid & 15;

    float vv[4][16];
#pragma unroll
    for (int bb = 0; bb < 4; ++bb) {
        int b = bg * 4 + bb;
        const float4* vp = (const float4*)(v + ((size_t)b * NJ + j) * 16);
#pragma unroll
        for (int o4 = 0; o4 < 4; ++o4) {
            float4 f = vp[o4];
            vv[bb][o4*4+0] = f.x; vv[bb][o4*4+1] = f.y;
            vv[bb][o4*4+2] = f.z; vv[bb][o4*4+3] = f.w;
        }
    }

#pragma unroll
    for (int k = 0; k < 4; ++k) {
        int il = iq + 16 * k;
        int ig = i0 + il;
        const float* wr = &wsh[il * LDW];
        float4 ua[4], ub[4];
#pragma unroll
        for (int bb = 0; bb < 4; ++bb) {
            int b = bg * 4 + bb;
            const float4* up = (const float4*)(u + ((size_t)b * NI + ig) * 8);
            ua[bb] = up[0];
            ub[bb] = up[1];
        }
        float acc[4] = {0.f, 0.f, 0.f, 0.f};
#pragma unroll
        for (int o = 0; o < 16; ++o) {
            float4 w0 = *(const float4*)&wr[o * 8];
            float4 w1 = *(const float4*)&wr[o * 8 + 4];
#pragma unroll
            for (int bb = 0; bb < 4; ++bb) {
                float dot = w0.x*ua[bb].x + w0.y*ua[bb].y + w0.z*ua[bb].z + w0.w*ua[bb].w
                          + w1.x*ub[bb].x + w1.y*ub[bb].y + w1.z*ub[bb].z + w1.w*ub[bb].w;
                acc[bb] = fmaf(vv[bb][o], dot, acc[bb]);
            }
        }
#pragma unroll
        for (int bb = 0; bb < 4; ++bb) {
            int b = bg * 4 + bb;
            size_t idx = ((size_t)b * NJ + j) * NI + ig;
            blog[idx] = accumulate ? (blog[idx] + acc[bb]) : acc[bb];
        }
    }
}

// ---------------------------------------------------------------------------
// FC GEMM fp32 (round 2, proven).
// ---------------------------------------------------------------------------
template<bool RELU>
__global__ __launch_bounds__(256, 4) void fc_gemm(
        const float* __restrict__ in, const float* __restrict__ w,
        const float* __restrict__ bias, float* __restrict__ out,
        int M, int N, int Kd) {
    constexpr int KC  = 32;
    constexpr int LDA = 68;
    __shared__ float Ash[KC * LDA];
    __shared__ float Bsh[KC * LDA];

    const int tid = threadIdx.x;
    const int n0 = blockIdx.x * 64;

    const int tn = tid & 15;
    const int tm = tid >> 4;

    float acc[4][4] = {{0.f}};

    for (int k0 = 0; k0 < Kd; k0 += KC) {
#pragma unroll
        for (int it = 0; it < 2; ++it) {
            int idx = tid + it * 256;
            int n   = idx >> 3;
            int k4  = idx & 7;
            int k   = k0 + k4 * 4;
            float4 w4 = make_float4(0.f, 0.f, 0.f, 0.f);
            int ng = n0 + n;
            if (ng < N) {
                const float* wp = w + (size_t)ng * Kd + k;
                if (k + 3 < Kd) {
                    w4 = *(const float4*)wp;
                } else {
                    if (k + 0 < Kd) w4.x = wp[0];
                    if (k + 1 < Kd) w4.y = wp[1];
                    if (k + 2 < Kd) w4.z = wp[2];
                    if (k + 3 < Kd) w4.w = wp[3];
                }
            }
            Ash[(k4 * 4 + 0) * LDA + n] = w4.x;
            Ash[(k4 * 4 + 1) * LDA + n] = w4.y;
            Ash[(k4 * 4 + 2) * LDA + n] = w4.z;
            Ash[(k4 * 4 + 3) * LDA + n] = w4.w;
        }
#pragma unroll
        for (int it = 0; it < 2; ++it) {
            int idx = tid + it * 256;
            int m   = idx >> 3;
            int k4  = idx & 7;
            int k   = k0 + k4 * 4;
            float4 x4 = make_float4(0.f, 0.f, 0.f, 0.f);
            if (m < M) {
                const float* xp = in + (size_t)m * Kd + k;
                if (k + 3 < Kd) {
                    x4 = *(const float4*)xp;
                } else {
                    if (k + 0 < Kd) x4.x = xp[0];
                    if (k + 1 < Kd) x4.y = xp[1];
                    if (k + 2 < Kd) x4.z = xp[2];
                    if (k + 3 < Kd) x4.w = xp[3];
                }
            }
            Bsh[(k4 * 4 + 0) * LDA + m] = x4.x;
            Bsh[(k4 * 4 + 1) * LDA + m] = x4.y;
            Bsh[(k4 * 4 + 2) * LDA + m] = x4.z;
            Bsh[(k4 * 4 + 3) * LDA + m] = x4.w;
        }
        __syncthreads();
#pragma unroll
        for (int kk = 0; kk < KC; ++kk) {
            float4 a4 = *(const float4*)&Ash[kk * LDA + tn * 4];
            float4 b4 = *(const float4*)&Bsh[kk * LDA + tm * 4];
            float av[4] = {a4.x, a4.y, a4.z, a4.w};
            float bv[4] = {b4.x, b4.y, b4.z, b4.w};
#pragma unroll
            for (int i = 0; i < 4; ++i)
#pragma unroll
                for (int j = 0; j < 4; ++j)
                    acc[i][j] = fmaf(av[i], bv[j], acc[i][j]);
        }
        __syncthreads();
    }

#pragma unroll
    for (int i = 0; i < 4; ++i) {
        int ng = n0 + tn * 4 + i;
        if (ng >= N) continue;
        float bs = bias[ng];
#pragma unroll
        for (int j = 0; j < 4; ++j) {
            int m = tm * 4 + j;
            if (m >= M) continue;
            float vv = acc[i][j] + bs;
            if (RELU) vv = fmaxf(vv, 0.f);
            out[(size_t)m * N + ng] = vv;
        }
    }
}

// ---------------------------------------------------------------------------
extern "C" void kernel_launch(void* const* d_in, const int* in_sizes, int n_in,
                              void* d_out, int out_size, void* d_ws, size_t ws_size,
                              hipStream_t stream) {
    const float* x     = (const float*)d_in[0];
    const float* w1    = (const float*)d_in[1];
    const float* b1    = (const float*)d_in[2];
    const float* w2    = (const float*)d_in[3];
    const float* b2    = (const float*)d_in[4];
    const float* w3    = (const float*)d_in[5];
    const float* b3    = (const float*)d_in[6];
    const float* w4    = (const float*)d_in[7];
    const float* b4    = (const float*)d_in[8];
    const float* w5    = (const float*)d_in[9];
    const float* b5    = (const float*)d_in[10];
    const float* pc_w  = (const float*)d_in[11];
    const float* pc_b  = (const float*)d_in[12];
    const float* capsW = (const float*)d_in[13];
    const float* fc1_w = (const float*)d_in[14];
    const float* fc1_b = (const float*)d_in[15];
    const float* fc2_w = (const float*)d_in[16];
    const float* fc2_b = (const float*)d_in[17];
    const float* fc3_w = (const float*)d_in[18];
    const float* fc3_b = (const float*)d_in[19];
    float* outp = (float*)d_out;

    // ws layout: A (80 MB) | Bb (20 MB) | Dd (4 MB) | weight planes (gated)
    char* ws = (char*)d_ws;
    float* A  = (float*)ws;
    float* Bb = (float*)(ws + ((size_t)80 << 20));
    float* Dd = (float*)(ws + ((size_t)100 << 20));
    float* blog  = A;
    float* csm   = A + 7446528;
    float* ppart = A + 2 * 7446528;
    float* vcap = Dd;
    float* f1   = Dd + 131072;
    float* f2   = Dd + 131072 + 262144;

    // weight-plane arena (hi then lo per layer), row stride Kp = ceil(Ktot/32)*32
    // Kp: w1 384, w2 2400, w3 2304, w4 3456, w5 3456, pc 2304
    const size_t WPL_ELEMS = 2ull * (96*384 + 256*2400 + 384*2304 +
                                     384*3456 + 256*3456 + 256*2304);
    const size_t WPL_NEED  = ((size_t)104 << 20) + WPL_ELEMS * 2;
    const bool wsplit = ws_size >= WPL_NEED;
    unsigned short* wp = (unsigned short*)(ws + ((size_t)104 << 20));
    unsigned short *w1h=nullptr,*w1l=nullptr,*w2h=nullptr,*w2l=nullptr,
                   *w3h=nullptr,*w3l=nullptr,*w4h=nullptr,*w4l=nullptr,
                   *w5h=nullptr,*w5l=nullptr,*pch=nullptr,*pcl=nullptr;
    if (wsplit) {
        size_t off = 0;
        auto alloc2 = [&](size_t n, unsigned short** h, unsigned short** l) {
            *h = wp + off; *l = wp + off + n; off += 2 * n;
        };
        alloc2((size_t)96*384,  &w1h, &w1l);
        alloc2((size_t)256*2400, &w2h, &w2l);
        alloc2((size_t)384*2304, &w3h, &w3l);
        alloc2((size_t)384*3456, &w4h, &w4l);
        alloc2((size_t)256*3456, &w5h, &w5l);
        alloc2((size_t)256*2304, &pch, &pcl);
        split_w<<<dim3(ceil_div(96*384, 256)), dim3(256), 0, stream>>>(
            w1, w1h, w1l, 363, 384, 96*384);
        split_w<<<dim3(ceil_div(256*2400, 256)), dim3(256), 0, stream>>>(
            w2, w2h, w2l, 2400, 2400, 256*2400);
        split_w<<<dim3(ceil_div(384*2304, 256)), dim3(256), 0, stream>>>(
            w3, w3h, w3l, 2304, 2304, 384*2304);
        split_w<<<dim3(ceil_div(384*3456, 256)), dim3(256), 0, stream>>>(
            w4, w4h, w4l, 3456, 3456, 384*3456);
        split_w<<<dim3(ceil_div(256*3456, 256)), dim3(256), 0, stream>>>(
            w5, w5h, w5l, 3456, 3456, 256*3456);
        split_w<<<dim3(ceil_div(256*2304, 256)), dim3(256), 0, stream>>>(
            pc_w, pch, pcl, 2304, 2304, 256*2304);
    }

    const int B = BATCH;

    // ---- conv stack ----
    // conv1: fp32 x -> fp32 A  [64,96,55,55]
    conv_mfma<11, 4, 0, 55, true, 96, false, false>
        <<<dim3(3025, 1), dim3(256), 0, stream>>>(
        x, w1, w1h, w1l, b1, A, 3, 96, 227, 384);
    // pool1: fp32 A -> packed Bb [64,96,27,27]
    maxpool_pack<<<dim3(ceil_div(B * 96 * 27 * 27, 256)), dim3(256), 0, stream>>>(
        A, (unsigned*)Bb, B * 96, 55, 55, 27, 27, 3, 2, 0);
    // conv2: packed Bb -> fp32 A [64,256,27,27]
    conv_mfma<5, 1, 2, 27, true, 128, true, false>
        <<<dim3(729, 2), dim3(256), 0, stream>>>(
        Bb, w2, w2h, w2l, b2, A, 96, 256, 27, 2400);
    // pool2: fp32 A -> packed Bb [64,256,14,14]
    maxpool_pack<<<dim3(ceil_div(B * 256 * 14 * 14, 256)), dim3(256), 0, stream>>>(
        A, (unsigned*)Bb, B * 256, 27, 27, 14, 14, 3, 2, 1);
    // conv3: packed Bb -> packed A [64,384,14,14]
    conv_mfma<3, 1, 1, 14, true, 128, true, true>
        <<<dim3(196, 3), dim3(256), 0, stream>>>(
        Bb, w3, w3h, w3l, b3, A, 256, 384, 14, 2304);
    // conv4: packed A -> packed Bb
    conv_mfma<3, 1, 1, 14, true, 128, true, true>
        <<<dim3(196, 3), dim3(256), 0, stream>>>(
        A, w4, w4h, w4l, b4, Bb, 384, 384, 14, 3456);
    // conv5: packed Bb -> fp32 A [64,256,14,14]
    conv_mfma<3, 1, 1, 14, true, 128, true, false>
        <<<dim3(196, 2), dim3(256), 0, stream>>>(
        Bb, w5, w5h, w5l, b5, A, 384, 256, 14, 3456);
    // pool5: fp32 A -> packed Bb [64,256,6,6]
    maxpool_pack<<<dim3(ceil_div(B * 256 * 6 * 6, 256)), dim3(256), 0, stream>>>(
        A, (unsigned*)Bb, B * 256, 14, 14, 6, 6, 3, 2, 0);
    // primarycaps: packed Bb -> fp32 A [64,256,6,6]
    conv_mfma<3, 1, 1, 6, false, 64, true, false>
        <<<dim3(36, 4), dim3(256), 0, stream>>>(
        Bb, pc_w, pch, pcl, pc_b, A, 256, 256, 6, 2304);
    squash_u<<<dim3(ceil_div(B * 1152, 256)), dim3(256), 0, stream>>>(A, Bb, B * 1152);
    // u in Bb [64,1152,8]

    // ---- dynamic routing (3 iters) ----
    dim3 rgrid(NIC, NJ);
    route_s_w<<<rgrid, dim3(256), 0, stream>>>(csm, Bb, capsW, ppart, 1);
    reduce_squash<<<dim3(BJ / 4), dim3(64), 0, stream>>>(ppart, vcap);
    route_bupd_w<<<rgrid, dim3(256), 0, stream>>>(Bb, capsW, vcap, blog, 0);
    softmax_j<<<dim3(ceil_div(B * NI, 256)), dim3(256), 0, stream>>>(
        blog, csm, B, NJ, NI);
    route_s_w<<<rgrid, dim3(256), 0, stream>>>(csm, Bb, capsW, ppart, 0);
    reduce_squash<<<dim3(BJ / 4), dim3(64), 0, stream>>>(ppart, vcap);
    route_bupd_w<<<rgrid, dim3(256), 0, stream>>>(Bb, capsW, vcap, blog, 1);
    softmax_j<<<dim3(ceil_div(B * NI, 256)), dim3(256), 0, stream>>>(
        blog, csm, B, NJ, NI);
    route_s_w<<<rgrid, dim3(256), 0, stream>>>(csm, Bb, capsW, ppart, 0);
    reduce_squash<<<dim3(BJ / 4), dim3(64), 0, stream>>>(ppart, vcap);

    // ---- MLP head ----
    fc_gemm<true><<<dim3(64), dim3(256), 0, stream>>>(vcap, fc1_w, fc1_b, f1, B, 4096, 1616);
    fc_gemm<true><<<dim3(64), dim3(256), 0, stream>>>(f1, fc2_w, fc2_b, f2, B, 4096, 4096);
    fc_gemm<false><<<dim3(2), dim3(256), 0, stream>>>(f2, fc3_w, fc3_b, outp, B, 101, 4096);
}